// Round 11
// baseline (395.694 us; speedup 1.0000x reference)
//
#include <hip/hip_runtime.h>
#include <hip/hip_bf16.h>

#define NN 8192
#define DD 384
#define NE 262144
#define NR 4
#define NL 2
#define NB 64

typedef __attribute__((ext_vector_type(8))) short bf16x8;
typedef __attribute__((ext_vector_type(4))) float f32x4;

__device__ __forceinline__ unsigned short f2bf(float f) {
  unsigned u = __float_as_uint(f);
  unsigned r = (u + 0x7fffu + ((u >> 16) & 1u)) >> 16;
  return (unsigned short)r;
}
__device__ __forceinline__ unsigned pack_bf2(float lo, float hi) {
  return (unsigned)f2bf(lo) | ((unsigned)f2bf(hi) << 16);
}
__device__ __forceinline__ float bflo(unsigned u) { return __uint_as_float(u << 16); }
__device__ __forceinline__ float bfhi(unsigned u) { return __uint_as_float(u & 0xffff0000u); }
__device__ __forceinline__ void gl_lds16(const void* g, void* l) {
  __builtin_amdgcn_global_load_lds(
      (const __attribute__((address_space(1))) unsigned int*)g,
      (__attribute__((address_space(3))) unsigned int*)l, 16, 0, 0);
}
__device__ __forceinline__ float dot8(uint4 a, uint4 b) {
  return bflo(a.x) * bflo(b.x) + bfhi(a.x) * bfhi(b.x) +
         bflo(a.y) * bflo(b.y) + bfhi(a.y) * bfhi(b.y) +
         bflo(a.z) * bflo(b.z) + bfhi(a.z) * bfhi(b.z) +
         bflo(a.w) * bflo(b.w) + bfhi(a.w) * bfhi(b.w);
}

// ---------------- workspace zeroing ----------------
__global__ void k_zero(uint4* __restrict__ p, int n4) {
  int i = blockIdx.x * 256 + threadIdx.x;
  if (i < n4) p[i] = make_uint4(0, 0, 0, 0);
}

// ---------------- BatchNorm column sums (256 blocks x 32 rows) ----------------
__global__ void k_colstats(const float* __restrict__ x, float* __restrict__ musum,
                           float* __restrict__ msqsum) {
  int c = threadIdx.x;            // 384
  int r0 = blockIdx.x * 32;       // 256 blocks
  float s = 0.f, s2 = 0.f;
  for (int r = 0; r < 32; ++r) {
    float v = x[(size_t)(r0 + r) * DD + c];
    s += v; s2 += v * v;
  }
  atomicAdd(&musum[c], s);
  atomicAdd(&msqsum[c], s2);
}

// h = gamma*(x-mu)*rstd + beta ; ninv = 1/||h||_row ; h_bf = bf16(h)
__global__ void k_bn(const float* __restrict__ x, const float* __restrict__ gamma,
                     const float* __restrict__ beta, const float* __restrict__ musum,
                     const float* __restrict__ msqsum, float* __restrict__ h,
                     short* __restrict__ h_bf, float* __restrict__ ninv) {
  int n = blockIdx.x;
  int t = threadIdx.x;  // 64
  float ss = 0.f;
#pragma unroll
  for (int i = 0; i < 6; ++i) {
    int c = t + i * 64;
    float m = musum[c] * (1.f / NN);
    float var = msqsum[c] * (1.f / NN) - m * m;
    float v = gamma[c] * (x[(size_t)n * DD + c] - m) * rsqrtf(var + 1e-5f) + beta[c];
    h[(size_t)n * DD + c] = v;
    h_bf[(size_t)n * DD + c] = (short)f2bf(v);
    ss += v * v;
  }
#pragma unroll
  for (int m = 32; m; m >>= 1) ss += __shfl_xor(ss, m, 64);
  if (t == 0) ninv[n] = rsqrtf(ss);
}

// ---------------- per-(dst,rel) histogram ----------------
__global__ void k_counts(const int* __restrict__ ei, const int* __restrict__ et,
                         int* __restrict__ c_rel) {
  int e = blockIdx.x * blockDim.x + threadIdx.x;
  if (e >= NE) return;
  int dst = ei[NE + e];
  atomicAdd(&c_rel[dst * NR + et[e]], 1);
}

// exclusive scan of c_rel (32768) -> rp2[32769], cursor copy
__global__ void k_scan(const int* __restrict__ c_rel, int* __restrict__ rp2,
                       int* __restrict__ cursor) {
  __shared__ int part[1024];
  int t = threadIdx.x;
  int base = t * 32;
  int v[32]; int s = 0;
#pragma unroll
  for (int i = 0; i < 32; ++i) { v[i] = c_rel[base + i]; s += v[i]; }
  part[t] = s;
  __syncthreads();
  for (int off = 1; off < 1024; off <<= 1) {
    int add = (t >= off) ? part[t - off] : 0;
    __syncthreads();
    part[t] += add;
    __syncthreads();
  }
  int run = (t == 0) ? 0 : part[t - 1];
  if (t == 0) rp2[0] = 0;
#pragma unroll
  for (int i = 0; i < 32; ++i) {
    cursor[base + i] = run;
    run += v[i];
    rp2[base + i + 1] = run;
  }
}

// ---------------- CSR fill (sorted by dst, then relation) ----------------
__global__ void k_fill(const int* __restrict__ ei, const int* __restrict__ et,
                       int* __restrict__ cursor, int* __restrict__ meta) {
  int e = blockIdx.x * blockDim.x + threadIdx.x;
  if (e >= NE) return;
  int src = ei[e], dst = ei[NE + e];
  int pos = atomicAdd(&cursor[dst * NR + et[e]], 1);
  meta[pos] = src;
}

// ---------------- edge cosine weights over sorted CSR (dst-local) --------------
__global__ void k_we2(const short* __restrict__ hb, const float* __restrict__ ninv,
                      const int* __restrict__ rp2, const int* __restrict__ meta,
                      float* __restrict__ wsort) {
  int n = blockIdx.x;
  int g = threadIdx.x >> 4, sl = threadIdx.x & 15;  // 256 threads
  int beg = rp2[n * 4], end = rp2[n * 4 + 4];
  if (beg == end) return;
  const uint4* hd = (const uint4*)(hb + (size_t)n * DD);
  uint4 b0 = hd[sl], b1 = hd[16 + sl], b2 = hd[32 + sl];
  float nd = ninv[n];
  for (int s = beg + g; s < end; s += 16) {
    int src = meta[s];
    const uint4* hs = (const uint4*)(hb + (size_t)src * DD);
    float acc = dot8(hs[sl], b0) + dot8(hs[16 + sl], b1) + dot8(hs[32 + sl], b2);
#pragma unroll
    for (int m = 8; m; m >>= 1) acc += __shfl_xor(acc, m, 64);
    if (sl == 0) wsort[s] = acc * ninv[src] * nd;
  }
}

// ---------------- per-relation aggregation of h (bf16 in/out), 4-deep unroll ------
__global__ void k_aggrel(const short* __restrict__ hb, const int* __restrict__ rp2,
                         const int* __restrict__ meta, const float* __restrict__ wsort,
                         const float* __restrict__ nc, short* __restrict__ Agg,
                         float* __restrict__ SC, int layer) {
  int n = blockIdx.x;
  int t = threadIdx.x;       // 384
  int r = t / 96;            // relation group
  int i = t - r * 96;        // 0..95, owns cols [4i, 4i+4)
  int beg = rp2[n * 4 + r], end = rp2[n * 4 + r + 1];
  float a0 = 0, a1 = 0, a2 = 0, a3 = 0, s = 0;
  int e = beg;
  for (; e + 3 < end; e += 4) {
    int s0 = meta[e], s1 = meta[e + 1], s2 = meta[e + 2], s3 = meta[e + 3];
    float w0 = wsort[e], w1 = wsort[e + 1], w2 = wsort[e + 2], w3 = wsort[e + 3];
    uint2 u0 = ((const uint2*)(hb + (size_t)s0 * DD))[i];
    uint2 u1 = ((const uint2*)(hb + (size_t)s1 * DD))[i];
    uint2 u2 = ((const uint2*)(hb + (size_t)s2 * DD))[i];
    uint2 u3 = ((const uint2*)(hb + (size_t)s3 * DD))[i];
    a0 += w0 * bflo(u0.x) + w1 * bflo(u1.x) + w2 * bflo(u2.x) + w3 * bflo(u3.x);
    a1 += w0 * bfhi(u0.x) + w1 * bfhi(u1.x) + w2 * bfhi(u2.x) + w3 * bfhi(u3.x);
    a2 += w0 * bflo(u0.y) + w1 * bflo(u1.y) + w2 * bflo(u2.y) + w3 * bflo(u3.y);
    a3 += w0 * bfhi(u0.y) + w1 * bfhi(u1.y) + w2 * bfhi(u2.y) + w3 * bfhi(u3.y);
    s += w0 + w1 + w2 + w3;
  }
  for (; e < end; ++e) {
    int s0 = meta[e];
    float w0 = wsort[e];
    uint2 u0 = ((const uint2*)(hb + (size_t)s0 * DD))[i];
    a0 += w0 * bflo(u0.x); a1 += w0 * bfhi(u0.x);
    a2 += w0 * bflo(u0.y); a3 += w0 * bfhi(u0.y);
    s += w0;
  }
  int c = end - beg;
  float f = 1.f / (nc[layer * 4 + r] * (float)(c > 1 ? c : 1));
  uint2 o;
  o.x = pack_bf2(a0 * f, a1 * f);
  o.y = pack_bf2(a2 * f, a3 * f);
  ((uint2*)(Agg + (size_t)n * 1536 + r * 384))[i] = o;
  if (i == 0) SC[n * 4 + r] = s * f;
}

// ---------------- MP mean aggregation of rel_out (bf16), 4-deep unroll ------------
__global__ void k_aggmp(short* __restrict__ B1, const int* __restrict__ rp2,
                        const int* __restrict__ meta) {
  __shared__ float red[3][96][4];
  int n = blockIdx.x;
  int t = threadIdx.x;  // 384
  int g = t / 96, i = t - g * 96;
  int beg = rp2[n * 4], end = rp2[n * 4 + 4];
  float a0 = 0, a1 = 0, a2 = 0, a3 = 0;
  int e = beg + g;
  for (; e + 12 < end; e += 16) {
    int s0 = meta[e], s1 = meta[e + 4], s2 = meta[e + 8], s3 = meta[e + 12];
    uint2 u0 = ((const uint2*)(B1 + (size_t)s0 * 768 + 384))[i];
    uint2 u1 = ((const uint2*)(B1 + (size_t)s1 * 768 + 384))[i];
    uint2 u2 = ((const uint2*)(B1 + (size_t)s2 * 768 + 384))[i];
    uint2 u3 = ((const uint2*)(B1 + (size_t)s3 * 768 + 384))[i];
    a0 += bflo(u0.x) + bflo(u1.x) + bflo(u2.x) + bflo(u3.x);
    a1 += bfhi(u0.x) + bfhi(u1.x) + bfhi(u2.x) + bfhi(u3.x);
    a2 += bflo(u0.y) + bflo(u1.y) + bflo(u2.y) + bflo(u3.y);
    a3 += bfhi(u0.y) + bfhi(u1.y) + bfhi(u2.y) + bfhi(u3.y);
  }
  for (; e < end; e += 4) {
    int s0 = meta[e];
    uint2 u = ((const uint2*)(B1 + (size_t)s0 * 768 + 384))[i];
    a0 += bflo(u.x); a1 += bfhi(u.x);
    a2 += bflo(u.y); a3 += bfhi(u.y);
  }
  if (g) {
    red[g - 1][i][0] = a0; red[g - 1][i][1] = a1;
    red[g - 1][i][2] = a2; red[g - 1][i][3] = a3;
  }
  __syncthreads();
  if (g == 0) {
#pragma unroll
    for (int k = 0; k < 3; ++k) {
      a0 += red[k][i][0]; a1 += red[k][i][1];
      a2 += red[k][i][2]; a3 += red[k][i][3];
    }
    float inv = (end > beg) ? 1.f / (float)(end - beg) : 0.f;
    uint2 o;
    o.x = pack_bf2(a0 * inv, a1 * inv);
    o.y = pack_bf2(a2 * inv, a3 * inv);
    ((uint2*)(B1 + (size_t)n * 768))[i] = o;
  }
}

// ---------------- weight packing, both layers in one dispatch ----------------
__global__ void k_packall(const float* __restrict__ W_rel, const float* __restrict__ W_msg,
                          const float* __restrict__ W_self, short* __restrict__ Wcat,
                          short* __restrict__ Wcat2) {
  const int T1 = NL * 384 * 1536;
  const int T2 = NL * 384 * 768;
  int idx = blockIdx.x * blockDim.x + threadIdx.x;
  if (idx < T1) {
    int l = idx / (384 * 1536);
    int rem = idx - l * 384 * 1536;
    int i = rem / 1536, kk = rem - i * 1536;
    int r = kk / 384, k = kk - r * 384;
    Wcat[idx] = (short)f2bf(W_rel[(((size_t)(l * NR + r) * DD) + i) * DD + k]);
  } else if (idx < T1 + T2) {
    int j = idx - T1;
    int l = j / (384 * 768);
    int rem = j - l * 384 * 768;
    int i = rem / 768, kk = rem - i * 768;
    float v = (kk < 384) ? W_msg[((size_t)l * DD + i) * DD + kk]
                         : W_self[((size_t)l * DD + i) * DD + kk - 384];
    Wcat2[j] = (short)f2bf(v);
  }
}

// ---------------- bf16 MFMA NT GEMM, m97 structure: 128x128 tile -----------------
// 4 waves (each 64x64 = 4x4 16x16x32 frags), BK=32, single-buffered 2-barrier loop,
// global_load_lds w=16, linear LDS (T2 swizzle is null on 2-phase — regime gate).
// 1-D grid 192 XCD-chunked: wg=(bid&7)*24+(bid>>3); bm=wg/3, bn=wg%3.
// MODE 0: C = relu(acc + sum_r SC[row][r]*b_rel[r][col]) -> bf16 B1[:,384:768]
// MODE 1: h = relu(acc + deg?b_msg + b_self) + h  (fp32), also h_bf = bf16(h)
template <int MODE>
__global__ __launch_bounds__(256) void k_gemm_mfma(
    const short* __restrict__ A, int K, const short* __restrict__ Bp,
    const float* __restrict__ SC, const float* __restrict__ brel_l,
    const float* __restrict__ bmsg_l, const float* __restrict__ bself_l,
    const int* __restrict__ rp2, float* __restrict__ h,
    short* __restrict__ h_bf, short* __restrict__ Cout) {
  __shared__ short As[128 * 32];   // 8KB: 128 rows x 32 cols, row-major
  __shared__ short Bs[128 * 32];
  int tid = threadIdx.x;
  int lane = tid & 63;
  int w = tid >> 6;              // 0..3
  int wr = w >> 1, wc = w & 1;   // wave tile origin (wr*64, wc*64)
  int bid = blockIdx.x;          // 192
  int wg = ((bid & 7) * 24) + (bid >> 3);
  int bm = wg / 3, bn = wg - bm * 3;

  // staging: chunk tid covers tile row tid/4 (0..63; +64 in 2nd load), k-octet tid%4
  int r0 = tid >> 2, c0 = (tid & 3) * 8;
  const short* Ag0 = A + (size_t)(bm * 128 + r0) * K + c0;
  const short* Ag1 = A + (size_t)(bm * 128 + r0 + 64) * K + c0;
  const short* Bg0 = Bp + (size_t)(bn * 128 + r0) * K + c0;
  const short* Bg1 = Bp + (size_t)(bn * 128 + r0 + 64) * K + c0;
  short* Asl0 = As + w * 512;          // wave-uniform LDS bases (lane*16B added by HW)
  short* Asl1 = As + 2048 + w * 512;
  short* Bsl0 = Bs + w * 512;
  short* Bsl1 = Bs + 2048 + w * 512;

  f32x4 acc[4][4] = {};
  int fr = lane & 15, fk = (lane >> 4) * 8;
  for (int k0 = 0; k0 < K; k0 += 32) {
    __syncthreads();  // previous iteration's LDS reads complete
    gl_lds16(Ag0 + k0, Asl0);
    gl_lds16(Ag1 + k0, Asl1);
    gl_lds16(Bg0 + k0, Bsl0);
    gl_lds16(Bg1 + k0, Bsl1);
    __syncthreads();  // staging drained (vmcnt(0) before barrier)
    bf16x8 a[4], b[4];
#pragma unroll
    for (int i = 0; i < 4; ++i)
      a[i] = *(const bf16x8*)&As[(wr * 64 + i * 16 + fr) * 32 + fk];
#pragma unroll
    for (int j = 0; j < 4; ++j)
      b[j] = *(const bf16x8*)&Bs[(wc * 64 + j * 16 + fr) * 32 + fk];
#pragma unroll
    for (int i = 0; i < 4; ++i)
#pragma unroll
      for (int j = 0; j < 4; ++j)
        acc[i][j] = __builtin_amdgcn_mfma_f32_16x16x32_bf16(a[i], b[j], acc[i][j], 0, 0, 0);
  }

  // epilogue: C/D layout col=lane&15, row=(lane>>4)*4+reg
  int cr = (lane >> 4) * 4;
  int cc = lane & 15;
#pragma unroll
  for (int i = 0; i < 4; ++i) {
#pragma unroll
    for (int jj = 0; jj < 4; ++jj) {
      int row = bm * 128 + wr * 64 + i * 16 + cr + jj;
      if (MODE == 0) {
        float4 sc = *(const float4*)&SC[row * 4];
#pragma unroll
        for (int j = 0; j < 4; ++j) {
          int col = bn * 128 + wc * 64 + j * 16 + cc;
          float v = acc[i][j][jj] + sc.x * brel_l[col] + sc.y * brel_l[384 + col] +
                    sc.z * brel_l[768 + col] + sc.w * brel_l[1152 + col];
          Cout[(size_t)row * 768 + 384 + col] = (short)f2bf(fmaxf(v, 0.f));
        }
      } else {
        float bmul = (rp2[(row + 1) * 4] > rp2[row * 4]) ? 1.f : 0.f;
#pragma unroll
        for (int j = 0; j < 4; ++j) {
          int col = bn * 128 + wc * 64 + j * 16 + cc;
          float v = acc[i][j][jj] + bmul * bmsg_l[col] + bself_l[col];
          float o = fmaxf(v, 0.f) + h[(size_t)row * DD + col];
          h[(size_t)row * DD + col] = o;
          h_bf[(size_t)row * DD + col] = (short)f2bf(o);
        }
      }
    }
  }
}

// ---------------- final per-batch mean ----------------
__global__ void k_out(const float* __restrict__ h, float* __restrict__ out) {
  int b = blockIdx.x;   // 64
  int c = threadIdx.x;  // 384
  float s = 0.f;
  for (int j = 0; j < 128; ++j) s += h[(size_t)(b * 128 + j) * DD + c];
  out[b * DD + c] = s * (1.f / 128.f);
}

extern "C" void kernel_launch(void* const* d_in, const int* in_sizes, int n_in,
                              void* d_out, int out_size, void* d_ws, size_t ws_size,
                              hipStream_t stream) {
  const float* x      = (const float*)d_in[0];
  const int*   ei     = (const int*)d_in[1];
  const int*   et     = (const int*)d_in[2];
  const float* gamma  = (const float*)d_in[3];
  const float* beta   = (const float*)d_in[4];
  const float* W_rel  = (const float*)d_in[5];
  const float* b_rel  = (const float*)d_in[6];
  const float* nc     = (const float*)d_in[7];
  const float* W_msg  = (const float*)d_in[8];
  const float* b_msg  = (const float*)d_in[9];
  const float* W_self = (const float*)d_in[10];
  const float* b_self = (const float*)d_in[11];
  float* out = (float*)d_out;

  char* ws = (char*)d_ws;
  size_t off = 0;
  auto alloc = [&](size_t bytes) -> void* {
    void* p = ws + off;
    off = (off + bytes + 255) & ~(size_t)255;
    return p;
  };
  float* h      = (float*)alloc((size_t)NN * DD * 4);
  short* h_bf   = (short*)alloc((size_t)NN * DD * 2);
  short* Agg    = (short*)alloc((size_t)NN * 1536 * 2);
  short* B1     = (short*)alloc((size_t)NN * 768 * 2);
  short* Wcat   = (short*)alloc((size_t)NL * 384 * 1536 * 2);
  short* Wcat2  = (short*)alloc((size_t)NL * 384 * 768 * 2);
  float* SC     = (float*)alloc((size_t)NN * 4 * 4);
  int*   meta   = (int*)alloc((size_t)NE * 4);
  float* wsort  = (float*)alloc((size_t)NE * 4);
  int*   rp2    = (int*)alloc((size_t)(NN * 4 + 1) * 4);
  int*   cursor = (int*)alloc((size_t)NN * 4 * 4);
  float* ninv   = (float*)alloc((size_t)NN * 4);
  char*  zb     = (char*)alloc(134144);  // musum|msqsum|c_rel contiguous, zeroed
  float* musum  = (float*)(zb);
  float* msqsum = (float*)(zb + 1536);
  int*   c_rel  = (int*)(zb + 3072);

  k_zero<<<(134144 / 16 + 255) / 256, 256, 0, stream>>>((uint4*)zb, 134144 / 16);
  k_colstats<<<256, 384, 0, stream>>>(x, musum, msqsum);
  k_bn<<<NN, 64, 0, stream>>>(x, gamma, beta, musum, msqsum, h, h_bf, ninv);
  k_counts<<<NE / 256, 256, 0, stream>>>(ei, et, c_rel);
  k_scan<<<1, 1024, 0, stream>>>(c_rel, rp2, cursor);
  k_fill<<<NE / 256, 256, 0, stream>>>(ei, et, cursor, meta);
  k_we2<<<NN, 256, 0, stream>>>(h_bf, ninv, rp2, meta, wsort);
  k_packall<<<(NL * 384 * 1536 + NL * 384 * 768 + 255) / 256, 256, 0, stream>>>(
      W_rel, W_msg, W_self, Wcat, Wcat2);

  for (int l = 0; l < NL; ++l) {
    k_aggrel<<<NN, 384, 0, stream>>>(h_bf, rp2, meta, wsort, nc, Agg, SC, l);
    k_gemm_mfma<0><<<192, 256, 0, stream>>>(
        Agg, 1536, Wcat + (size_t)l * 384 * 1536, SC, b_rel + l * NR * DD,
        nullptr, nullptr, nullptr, nullptr, nullptr, B1);
    k_aggmp<<<NN, 384, 0, stream>>>(B1, rp2, meta);
    k_gemm_mfma<1><<<192, 256, 0, stream>>>(
        B1, 768, Wcat2 + (size_t)l * 384 * 768, nullptr, nullptr,
        b_msg + l * DD, b_self + l * DD, rp2, h, h_bf, nullptr);
  }
  k_out<<<64, 384, 0, stream>>>(h, out);
}

// Round 12
// 295.432 us; speedup vs baseline: 1.3394x; 1.3394x over previous
//
#include <hip/hip_runtime.h>
#include <hip/hip_bf16.h>

#define NN 8192
#define DD 384
#define NE 262144
#define NR 4
#define NL 2
#define NB 64

typedef __attribute__((ext_vector_type(8))) short bf16x8;
typedef __attribute__((ext_vector_type(4))) float f32x4;

__device__ __forceinline__ unsigned short f2bf(float f) {
  unsigned u = __float_as_uint(f);
  unsigned r = (u + 0x7fffu + ((u >> 16) & 1u)) >> 16;
  return (unsigned short)r;
}
__device__ __forceinline__ unsigned pack_bf2(float lo, float hi) {
  return (unsigned)f2bf(lo) | ((unsigned)f2bf(hi) << 16);
}
__device__ __forceinline__ float bflo(unsigned u) { return __uint_as_float(u << 16); }
__device__ __forceinline__ float bfhi(unsigned u) { return __uint_as_float(u & 0xffff0000u); }
__device__ __forceinline__ void gl_lds16(const void* g, void* l) {
  __builtin_amdgcn_global_load_lds(
      (const __attribute__((address_space(1))) unsigned int*)g,
      (__attribute__((address_space(3))) unsigned int*)l, 16, 0, 0);
}
__device__ __forceinline__ float dot8(uint4 a, uint4 b) {
  return bflo(a.x) * bflo(b.x) + bfhi(a.x) * bfhi(b.x) +
         bflo(a.y) * bflo(b.y) + bfhi(a.y) * bfhi(b.y) +
         bflo(a.z) * bflo(b.z) + bfhi(a.z) * bfhi(b.z) +
         bflo(a.w) * bflo(b.w) + bfhi(a.w) * bfhi(b.w);
}

// ---------------- workspace zeroing ----------------
__global__ void k_zero(uint4* __restrict__ p, int n4) {
  int i = blockIdx.x * 256 + threadIdx.x;
  if (i < n4) p[i] = make_uint4(0, 0, 0, 0);
}

// ---------------- fused prologue: colstats | counts | packall ----------------
// 384 threads/block. blocks [0,256): BN column sums; [256,939): edge histogram;
// [939,5547): weight packing (both layers). All depend only on k_zero.
__global__ void k_pre(const float* __restrict__ x, float* __restrict__ musum,
                      float* __restrict__ msqsum, const int* __restrict__ ei,
                      const int* __restrict__ et, int* __restrict__ c_rel,
                      const float* __restrict__ W_rel, const float* __restrict__ W_msg,
                      const float* __restrict__ W_self, short* __restrict__ Wcat,
                      short* __restrict__ Wcat2) {
  int b = blockIdx.x;
  int t = threadIdx.x;
  if (b < 256) {
    int c = t;                 // 384
    int r0 = b * 32;
    float s = 0.f, s2 = 0.f;
    for (int r = 0; r < 32; ++r) {
      float v = x[(size_t)(r0 + r) * DD + c];
      s += v; s2 += v * v;
    }
    atomicAdd(&musum[c], s);
    atomicAdd(&msqsum[c], s2);
  } else if (b < 939) {
    int e = (b - 256) * 384 + t;
    if (e < NE) {
      int dst = ei[NE + e];
      atomicAdd(&c_rel[dst * NR + et[e]], 1);
    }
  } else {
    const int T1 = NL * 384 * 1536;
    int idx = (b - 939) * 384 + t;
    if (idx < T1) {
      int l = idx / (384 * 1536);
      int rem = idx - l * 384 * 1536;
      int i = rem / 1536, kk = rem - i * 1536;
      int r = kk / 384, k = kk - r * 384;
      Wcat[idx] = (short)f2bf(W_rel[(((size_t)(l * NR + r) * DD) + i) * DD + k]);
    } else {
      int j = idx - T1;
      int l = j / (384 * 768);
      int rem = j - l * 384 * 768;
      int i = rem / 768, kk = rem - i * 768;
      float v = (kk < 384) ? W_msg[((size_t)l * DD + i) * DD + kk]
                           : W_self[((size_t)l * DD + i) * DD + kk - 384];
      Wcat2[j] = (short)f2bf(v);
    }
  }
}

// h = gamma*(x-mu)*rstd + beta ; ninv = 1/||h||_row ; h_bf = bf16(h)
__global__ void k_bn(const float* __restrict__ x, const float* __restrict__ gamma,
                     const float* __restrict__ beta, const float* __restrict__ musum,
                     const float* __restrict__ msqsum, float* __restrict__ h,
                     short* __restrict__ h_bf, float* __restrict__ ninv) {
  int n = blockIdx.x;
  int t = threadIdx.x;  // 64
  float ss = 0.f;
#pragma unroll
  for (int i = 0; i < 6; ++i) {
    int c = t + i * 64;
    float m = musum[c] * (1.f / NN);
    float var = msqsum[c] * (1.f / NN) - m * m;
    float v = gamma[c] * (x[(size_t)n * DD + c] - m) * rsqrtf(var + 1e-5f) + beta[c];
    h[(size_t)n * DD + c] = v;
    h_bf[(size_t)n * DD + c] = (short)f2bf(v);
    ss += v * v;
  }
#pragma unroll
  for (int m = 32; m; m >>= 1) ss += __shfl_xor(ss, m, 64);
  if (t == 0) ninv[n] = rsqrtf(ss);
}

// exclusive scan of c_rel (32768) -> rp2[32769], cursor copy
__global__ void k_scan(const int* __restrict__ c_rel, int* __restrict__ rp2,
                       int* __restrict__ cursor) {
  __shared__ int part[1024];
  int t = threadIdx.x;
  int base = t * 32;
  int v[32]; int s = 0;
#pragma unroll
  for (int i = 0; i < 32; ++i) { v[i] = c_rel[base + i]; s += v[i]; }
  part[t] = s;
  __syncthreads();
  for (int off = 1; off < 1024; off <<= 1) {
    int add = (t >= off) ? part[t - off] : 0;
    __syncthreads();
    part[t] += add;
    __syncthreads();
  }
  int run = (t == 0) ? 0 : part[t - 1];
  if (t == 0) rp2[0] = 0;
#pragma unroll
  for (int i = 0; i < 32; ++i) {
    cursor[base + i] = run;
    run += v[i];
    rp2[base + i + 1] = run;
  }
}

// ---------------- CSR fill (sorted by dst, then relation) ----------------
__global__ void k_fill(const int* __restrict__ ei, const int* __restrict__ et,
                       int* __restrict__ cursor, int* __restrict__ meta) {
  int e = blockIdx.x * blockDim.x + threadIdx.x;
  if (e >= NE) return;
  int src = ei[e], dst = ei[NE + e];
  int pos = atomicAdd(&cursor[dst * NR + et[e]], 1);
  meta[pos] = src;
}

// ---------------- edge cosine weights over sorted CSR (dst-local) --------------
__global__ void k_we2(const short* __restrict__ hb, const float* __restrict__ ninv,
                      const int* __restrict__ rp2, const int* __restrict__ meta,
                      float* __restrict__ wsort) {
  int n = blockIdx.x;
  int g = threadIdx.x >> 4, sl = threadIdx.x & 15;  // 256 threads
  int beg = rp2[n * 4], end = rp2[n * 4 + 4];
  if (beg == end) return;
  const uint4* hd = (const uint4*)(hb + (size_t)n * DD);
  uint4 b0 = hd[sl], b1 = hd[16 + sl], b2 = hd[32 + sl];
  float nd = ninv[n];
  for (int s = beg + g; s < end; s += 16) {
    int src = meta[s];
    const uint4* hs = (const uint4*)(hb + (size_t)src * DD);
    float acc = dot8(hs[sl], b0) + dot8(hs[16 + sl], b1) + dot8(hs[32 + sl], b2);
#pragma unroll
    for (int m = 8; m; m >>= 1) acc += __shfl_xor(acc, m, 64);
    if (sl == 0) wsort[s] = acc * ninv[src] * nd;
  }
}

// ---------------- per-relation aggregation of h (bf16 in/out), 4-deep unroll ------
__global__ void k_aggrel(const short* __restrict__ hb, const int* __restrict__ rp2,
                         const int* __restrict__ meta, const float* __restrict__ wsort,
                         const float* __restrict__ nc, short* __restrict__ Agg,
                         float* __restrict__ SC, int layer) {
  int n = blockIdx.x;
  int t = threadIdx.x;       // 384
  int r = t / 96;            // relation group
  int i = t - r * 96;        // 0..95, owns cols [4i, 4i+4)
  int beg = rp2[n * 4 + r], end = rp2[n * 4 + r + 1];
  float a0 = 0, a1 = 0, a2 = 0, a3 = 0, s = 0;
  int e = beg;
  for (; e + 3 < end; e += 4) {
    int s0 = meta[e], s1 = meta[e + 1], s2 = meta[e + 2], s3 = meta[e + 3];
    float w0 = wsort[e], w1 = wsort[e + 1], w2 = wsort[e + 2], w3 = wsort[e + 3];
    uint2 u0 = ((const uint2*)(hb + (size_t)s0 * DD))[i];
    uint2 u1 = ((const uint2*)(hb + (size_t)s1 * DD))[i];
    uint2 u2 = ((const uint2*)(hb + (size_t)s2 * DD))[i];
    uint2 u3 = ((const uint2*)(hb + (size_t)s3 * DD))[i];
    a0 += w0 * bflo(u0.x) + w1 * bflo(u1.x) + w2 * bflo(u2.x) + w3 * bflo(u3.x);
    a1 += w0 * bfhi(u0.x) + w1 * bfhi(u1.x) + w2 * bfhi(u2.x) + w3 * bfhi(u3.x);
    a2 += w0 * bflo(u0.y) + w1 * bflo(u1.y) + w2 * bflo(u2.y) + w3 * bflo(u3.y);
    a3 += w0 * bfhi(u0.y) + w1 * bfhi(u1.y) + w2 * bfhi(u2.y) + w3 * bfhi(u3.y);
    s += w0 + w1 + w2 + w3;
  }
  for (; e < end; ++e) {
    int s0 = meta[e];
    float w0 = wsort[e];
    uint2 u0 = ((const uint2*)(hb + (size_t)s0 * DD))[i];
    a0 += w0 * bflo(u0.x); a1 += w0 * bfhi(u0.x);
    a2 += w0 * bflo(u0.y); a3 += w0 * bfhi(u0.y);
    s += w0;
  }
  int c = end - beg;
  float f = 1.f / (nc[layer * 4 + r] * (float)(c > 1 ? c : 1));
  uint2 o;
  o.x = pack_bf2(a0 * f, a1 * f);
  o.y = pack_bf2(a2 * f, a3 * f);
  ((uint2*)(Agg + (size_t)n * 1536 + r * 384))[i] = o;
  if (i == 0) SC[n * 4 + r] = s * f;
}

// ---------------- MP mean aggregation of rel_out (bf16), 4-deep unroll ------------
__global__ void k_aggmp(short* __restrict__ B1, const int* __restrict__ rp2,
                        const int* __restrict__ meta) {
  __shared__ float red[3][96][4];
  int n = blockIdx.x;
  int t = threadIdx.x;  // 384
  int g = t / 96, i = t - g * 96;
  int beg = rp2[n * 4], end = rp2[n * 4 + 4];
  float a0 = 0, a1 = 0, a2 = 0, a3 = 0;
  int e = beg + g;
  for (; e + 12 < end; e += 16) {
    int s0 = meta[e], s1 = meta[e + 4], s2 = meta[e + 8], s3 = meta[e + 12];
    uint2 u0 = ((const uint2*)(B1 + (size_t)s0 * 768 + 384))[i];
    uint2 u1 = ((const uint2*)(B1 + (size_t)s1 * 768 + 384))[i];
    uint2 u2 = ((const uint2*)(B1 + (size_t)s2 * 768 + 384))[i];
    uint2 u3 = ((const uint2*)(B1 + (size_t)s3 * 768 + 384))[i];
    a0 += bflo(u0.x) + bflo(u1.x) + bflo(u2.x) + bflo(u3.x);
    a1 += bfhi(u0.x) + bfhi(u1.x) + bfhi(u2.x) + bfhi(u3.x);
    a2 += bflo(u0.y) + bflo(u1.y) + bflo(u2.y) + bflo(u3.y);
    a3 += bfhi(u0.y) + bfhi(u1.y) + bfhi(u2.y) + bfhi(u3.y);
  }
  for (; e < end; e += 4) {
    int s0 = meta[e];
    uint2 u = ((const uint2*)(B1 + (size_t)s0 * 768 + 384))[i];
    a0 += bflo(u.x); a1 += bfhi(u.x);
    a2 += bflo(u.y); a3 += bfhi(u.y);
  }
  if (g) {
    red[g - 1][i][0] = a0; red[g - 1][i][1] = a1;
    red[g - 1][i][2] = a2; red[g - 1][i][3] = a3;
  }
  __syncthreads();
  if (g == 0) {
#pragma unroll
    for (int k = 0; k < 3; ++k) {
      a0 += red[k][i][0]; a1 += red[k][i][1];
      a2 += red[k][i][2]; a3 += red[k][i][3];
    }
    float inv = (end > beg) ? 1.f / (float)(end - beg) : 0.f;
    uint2 o;
    o.x = pack_bf2(a0 * inv, a1 * inv);
    o.y = pack_bf2(a2 * inv, a3 * inv);
    ((uint2*)(B1 + (size_t)n * 768))[i] = o;
  }
}

// ---------------- bf16 MFMA NT GEMM, double-buffered, XCD-chunked grid -----------
// 64x64 tile, 4 waves (each 32x32), BK=64, global_load_lds w=16, XOR-swizzled LDS
// (pre-swizzled global source + swizzled ds_read; LDS dest linear — rule #21).
// 1-D grid 768: wg=(bid&7)*96+(bid>>3); bm=wg/6, bn=wg%6.
// NOTE: 128^2 tile measured WORSE here (r11: 56us, 7% occ) — shape yields only
// 192 tiles at 128^2; this skinny-N GEMM needs the 768-block 64^2 grid.
// MODE 0: C = relu(acc + sum_r SC[row][r]*b_rel[r][col]) -> bf16 B1[:,384:768]
// MODE 1: h = relu(acc + deg?b_msg + b_self) + h  (fp32), also h_bf = bf16(h)
template <int MODE>
__global__ __launch_bounds__(256) void k_gemm_mfma(
    const short* __restrict__ A, int K, const short* __restrict__ Bp,
    const float* __restrict__ SC, const float* __restrict__ brel_l,
    const float* __restrict__ bmsg_l, const float* __restrict__ bself_l,
    const int* __restrict__ rp2, float* __restrict__ h,
    short* __restrict__ h_bf, short* __restrict__ Cout) {
  __shared__ short As[2][64 * 64];   // 8KB per buffer: 64 rows x 8 chunks(16B)
  __shared__ short Bs[2][64 * 64];   // chunk q' of row r holds global chunk q'^(r&7)
  int tid = threadIdx.x;
  int lane = tid & 63;
  int w = tid >> 6;              // 0..3
  int wr = w >> 1, wc = w & 1;   // wave tile origin (wr*32, wc*32)
  int bid = blockIdx.x;          // 768
  int wg = ((bid & 7) * 96) + (bid >> 3);
  int bm = wg / 6, bn = wg - bm * 6;

  int r0 = (w << 3) + (lane >> 3);        // rows 0..31 (set 0); set 1 adds 32
  int qg = (lane & 7) ^ (r0 & 7);         // (r0+32)&7 == r0&7
  const short* Ag0 = A + (size_t)(bm * 64 + r0) * K + qg * 8;
  const short* Ag1 = A + (size_t)(bm * 64 + r0 + 32) * K + qg * 8;
  const short* Bg0 = Bp + (size_t)(bn * 64 + r0) * K + qg * 8;
  const short* Bg1 = Bp + (size_t)(bn * 64 + r0 + 32) * K + qg * 8;

  auto stage = [&](int bi, int k0) {
    gl_lds16(Ag0 + k0, &As[bi][w * 512]);
    gl_lds16(Ag1 + k0, &As[bi][2048 + w * 512]);
    gl_lds16(Bg0 + k0, &Bs[bi][w * 512]);
    gl_lds16(Bg1 + k0, &Bs[bi][2048 + w * 512]);
  };

  f32x4 acc[2][2] = {};
  int fr = lane & 15, fq = lane >> 4;
  int nt = K >> 6;
  stage(0, 0);
  __syncthreads();
  for (int t = 0; t < nt; ++t) {
    if (t + 1 < nt) stage((t + 1) & 1, (t + 1) << 6);
    const short* Ab = As[t & 1];
    const short* Bb = Bs[t & 1];
#pragma unroll
    for (int kk = 0; kk < 2; ++kk) {
      bf16x8 a[2], b[2];
#pragma unroll
      for (int i = 0; i < 2; ++i) {
        int r = wr * 32 + i * 16 + fr;
        int qs = (kk * 4 + fq) ^ (r & 7);
        a[i] = *(const bf16x8*)&Ab[r * 64 + qs * 8];
      }
#pragma unroll
      for (int j = 0; j < 2; ++j) {
        int r = wc * 32 + j * 16 + fr;
        int qs = (kk * 4 + fq) ^ (r & 7);
        b[j] = *(const bf16x8*)&Bb[r * 64 + qs * 8];
      }
#pragma unroll
      for (int i = 0; i < 2; ++i)
#pragma unroll
        for (int j = 0; j < 2; ++j)
          acc[i][j] = __builtin_amdgcn_mfma_f32_16x16x32_bf16(a[i], b[j], acc[i][j], 0, 0, 0);
    }
    __syncthreads();
  }

  int cr = (lane >> 4) * 4;
  int cc = lane & 15;
#pragma unroll
  for (int i = 0; i < 2; ++i) {
#pragma unroll
    for (int jj = 0; jj < 4; ++jj) {
      int row = bm * 64 + wr * 32 + i * 16 + cr + jj;
      if (MODE == 0) {
        float4 sc = *(const float4*)&SC[row * 4];
#pragma unroll
        for (int j = 0; j < 2; ++j) {
          int col = bn * 64 + wc * 32 + j * 16 + cc;
          float v = acc[i][j][jj] + sc.x * brel_l[col] + sc.y * brel_l[384 + col] +
                    sc.z * brel_l[768 + col] + sc.w * brel_l[1152 + col];
          Cout[(size_t)row * 768 + 384 + col] = (short)f2bf(fmaxf(v, 0.f));
        }
      } else {
        float bmul = (rp2[(row + 1) * 4] > rp2[row * 4]) ? 1.f : 0.f;
#pragma unroll
        for (int j = 0; j < 2; ++j) {
          int col = bn * 64 + wc * 32 + j * 16 + cc;
          float v = acc[i][j][jj] + bmul * bmsg_l[col] + bself_l[col];
          float o = fmaxf(v, 0.f) + h[(size_t)row * DD + col];
          h[(size_t)row * DD + col] = o;
          h_bf[(size_t)row * DD + col] = (short)f2bf(o);
        }
      }
    }
  }
}

// ---------------- final per-batch mean ----------------
__global__ void k_out(const float* __restrict__ h, float* __restrict__ out) {
  int b = blockIdx.x;   // 64
  int c = threadIdx.x;  // 384
  float s = 0.f;
  for (int j = 0; j < 128; ++j) s += h[(size_t)(b * 128 + j) * DD + c];
  out[b * DD + c] = s * (1.f / 128.f);
}

extern "C" void kernel_launch(void* const* d_in, const int* in_sizes, int n_in,
                              void* d_out, int out_size, void* d_ws, size_t ws_size,
                              hipStream_t stream) {
  const float* x      = (const float*)d_in[0];
  const int*   ei     = (const int*)d_in[1];
  const int*   et     = (const int*)d_in[2];
  const float* gamma  = (const float*)d_in[3];
  const float* beta   = (const float*)d_in[4];
  const float* W_rel  = (const float*)d_in[5];
  const float* b_rel  = (const float*)d_in[6];
  const float* nc     = (const float*)d_in[7];
  const float* W_msg  = (const float*)d_in[8];
  const float* b_msg  = (const float*)d_in[9];
  const float* W_self = (const float*)d_in[10];
  const float* b_self = (const float*)d_in[11];
  float* out = (float*)d_out;

  char* ws = (char*)d_ws;
  size_t off = 0;
  auto alloc = [&](size_t bytes) -> void* {
    void* p = ws + off;
    off = (off + bytes + 255) & ~(size_t)255;
    return p;
  };
  float* h      = (float*)alloc((size_t)NN * DD * 4);
  short* h_bf   = (short*)alloc((size_t)NN * DD * 2);
  short* Agg    = (short*)alloc((size_t)NN * 1536 * 2);
  short* B1     = (short*)alloc((size_t)NN * 768 * 2);
  short* Wcat   = (short*)alloc((size_t)NL * 384 * 1536 * 2);
  short* Wcat2  = (short*)alloc((size_t)NL * 384 * 768 * 2);
  float* SC     = (float*)alloc((size_t)NN * 4 * 4);
  int*   meta   = (int*)alloc((size_t)NE * 4);
  float* wsort  = (float*)alloc((size_t)NE * 4);
  int*   rp2    = (int*)alloc((size_t)(NN * 4 + 1) * 4);
  int*   cursor = (int*)alloc((size_t)NN * 4 * 4);
  float* ninv   = (float*)alloc((size_t)NN * 4);
  char*  zb     = (char*)alloc(134144);  // musum|msqsum|c_rel contiguous, zeroed
  float* musum  = (float*)(zb);
  float* msqsum = (float*)(zb + 1536);
  int*   c_rel  = (int*)(zb + 3072);

  k_zero<<<(134144 / 16 + 255) / 256, 256, 0, stream>>>((uint4*)zb, 134144 / 16);
  k_pre<<<5547, 384, 0, stream>>>(x, musum, msqsum, ei, et, c_rel,
                                  W_rel, W_msg, W_self, Wcat, Wcat2);
  k_bn<<<NN, 64, 0, stream>>>(x, gamma, beta, musum, msqsum, h, h_bf, ninv);
  k_scan<<<1, 1024, 0, stream>>>(c_rel, rp2, cursor);
  k_fill<<<NE / 256, 256, 0, stream>>>(ei, et, cursor, meta);
  k_we2<<<NN, 256, 0, stream>>>(h_bf, ninv, rp2, meta, wsort);

  for (int l = 0; l < NL; ++l) {
    k_aggrel<<<NN, 384, 0, stream>>>(h_bf, rp2, meta, wsort, nc, Agg, SC, l);
    k_gemm_mfma<0><<<768, 256, 0, stream>>>(
        Agg, 1536, Wcat + (size_t)l * 384 * 1536, SC, b_rel + l * NR * DD,
        nullptr, nullptr, nullptr, nullptr, nullptr, B1);
    k_aggmp<<<NN, 384, 0, stream>>>(B1, rp2, meta);
    k_gemm_mfma<1><<<768, 256, 0, stream>>>(
        B1, 768, Wcat2 + (size_t)l * 384 * 768, nullptr, nullptr,
        b_msg + l * DD, b_self + l * DD, rp2, h, h_bf, nullptr);
  }
  k_out<<<64, 384, 0, stream>>>(h, out);
}

// Round 14
// 286.230 us; speedup vs baseline: 1.3824x; 1.0322x over previous
//
#include <hip/hip_runtime.h>
#include <hip/hip_bf16.h>
#include <hip/hip_fp8.h>

#define NN 8192
#define DD 384
#define NE 262144
#define NR 4
#define NL 2
#define NB 64

typedef __attribute__((ext_vector_type(8))) short bf16x8;
typedef __attribute__((ext_vector_type(4))) float f32x4;

__device__ __forceinline__ unsigned short f2bf(float f) {
  unsigned u = __float_as_uint(f);
  unsigned r = (u + 0x7fffu + ((u >> 16) & 1u)) >> 16;
  return (unsigned short)r;
}
__device__ __forceinline__ unsigned pack_bf2(float lo, float hi) {
  return (unsigned)f2bf(lo) | ((unsigned)f2bf(hi) << 16);
}
__device__ __forceinline__ float bflo(unsigned u) { return __uint_as_float(u << 16); }
__device__ __forceinline__ float bfhi(unsigned u) { return __uint_as_float(u & 0xffff0000u); }
__device__ __forceinline__ unsigned char f2f8(float f) {
  __hip_fp8_e4m3 v(f);
  return (unsigned char)v.__x;
}
__device__ __forceinline__ float f8b(unsigned u, int b) {
  __hip_fp8_e4m3 v;
  v.__x = (__hip_fp8_storage_t)((u >> (b * 8)) & 0xffu);
  return (float)v;
}
__device__ __forceinline__ void gl_lds16(const void* g, void* l) {
  __builtin_amdgcn_global_load_lds(
      (const __attribute__((address_space(1))) unsigned int*)g,
      (__attribute__((address_space(3))) unsigned int*)l, 16, 0, 0);
}
__device__ __forceinline__ float dot8(uint4 a, uint4 b) {
  return bflo(a.x) * bflo(b.x) + bfhi(a.x) * bfhi(b.x) +
         bflo(a.y) * bflo(b.y) + bfhi(a.y) * bfhi(b.y) +
         bflo(a.z) * bflo(b.z) + bfhi(a.z) * bfhi(b.z) +
         bflo(a.w) * bflo(b.w) + bfhi(a.w) * bfhi(b.w);
}

// ---------------- workspace zeroing ----------------
__global__ void k_zero(uint4* __restrict__ p, int n4) {
  int i = blockIdx.x * 256 + threadIdx.x;
  if (i < n4) p[i] = make_uint4(0, 0, 0, 0);
}

// ---------------- fused prologue: colstats | counts | packall ----------------
__global__ void k_pre(const float* __restrict__ x, float* __restrict__ musum,
                      float* __restrict__ msqsum, const int* __restrict__ ei,
                      const int* __restrict__ et, int* __restrict__ c_rel,
                      const float* __restrict__ W_rel, const float* __restrict__ W_msg,
                      const float* __restrict__ W_self, short* __restrict__ Wcat,
                      short* __restrict__ Wcat2) {
  int b = blockIdx.x;
  int t = threadIdx.x;
  if (b < 256) {
    int c = t;                 // 384
    int r0 = b * 32;
    float s = 0.f, s2 = 0.f;
    for (int r = 0; r < 32; ++r) {
      float v = x[(size_t)(r0 + r) * DD + c];
      s += v; s2 += v * v;
    }
    atomicAdd(&musum[c], s);
    atomicAdd(&msqsum[c], s2);
  } else if (b < 939) {
    int e = (b - 256) * 384 + t;
    if (e < NE) {
      int dst = ei[NE + e];
      atomicAdd(&c_rel[dst * NR + et[e]], 1);
    }
  } else {
    const int T1 = NL * 384 * 1536;
    int idx = (b - 939) * 384 + t;
    if (idx < T1) {
      int l = idx / (384 * 1536);
      int rem = idx - l * 384 * 1536;
      int i = rem / 1536, kk = rem - i * 1536;
      int r = kk / 384, k = kk - r * 384;
      Wcat[idx] = (short)f2bf(W_rel[(((size_t)(l * NR + r) * DD) + i) * DD + k]);
    } else {
      int j = idx - T1;
      int l = j / (384 * 768);
      int rem = j - l * 384 * 768;
      int i = rem / 768, kk = rem - i * 768;
      float v = (kk < 384) ? W_msg[((size_t)l * DD + i) * DD + kk]
                           : W_self[((size_t)l * DD + i) * DD + kk - 384];
      Wcat2[j] = (short)f2bf(v);
    }
  }
}

// h = gamma*(x-mu)*rstd + beta ; ninv = 1/||h||_row ; h_bf = bf16(h); h_f8 = fp8(h)
__global__ void k_bn(const float* __restrict__ x, const float* __restrict__ gamma,
                     const float* __restrict__ beta, const float* __restrict__ musum,
                     const float* __restrict__ msqsum, float* __restrict__ h,
                     short* __restrict__ h_bf, unsigned char* __restrict__ h_f8,
                     float* __restrict__ ninv) {
  int n = blockIdx.x;
  int t = threadIdx.x;  // 64
  float ss = 0.f;
#pragma unroll
  for (int i = 0; i < 6; ++i) {
    int c = t + i * 64;
    float m = musum[c] * (1.f / NN);
    float var = msqsum[c] * (1.f / NN) - m * m;
    float v = gamma[c] * (x[(size_t)n * DD + c] - m) * rsqrtf(var + 1e-5f) + beta[c];
    h[(size_t)n * DD + c] = v;
    h_bf[(size_t)n * DD + c] = (short)f2bf(v);
    h_f8[(size_t)n * DD + c] = f2f8(v);
    ss += v * v;
  }
#pragma unroll
  for (int m = 32; m; m >>= 1) ss += __shfl_xor(ss, m, 64);
  if (t == 0) ninv[n] = rsqrtf(ss);
}

// exclusive scan of c_rel (32768) -> rp2[32769], cursor copy
__global__ void k_scan(const int* __restrict__ c_rel, int* __restrict__ rp2,
                       int* __restrict__ cursor) {
  __shared__ int part[1024];
  int t = threadIdx.x;
  int base = t * 32;
  int v[32]; int s = 0;
#pragma unroll
  for (int i = 0; i < 32; ++i) { v[i] = c_rel[base + i]; s += v[i]; }
  part[t] = s;
  __syncthreads();
  for (int off = 1; off < 1024; off <<= 1) {
    int add = (t >= off) ? part[t - off] : 0;
    __syncthreads();
    part[t] += add;
    __syncthreads();
  }
  int run = (t == 0) ? 0 : part[t - 1];
  if (t == 0) rp2[0] = 0;
#pragma unroll
  for (int i = 0; i < 32; ++i) {
    cursor[base + i] = run;
    run += v[i];
    rp2[base + i + 1] = run;
  }
}

// ---------------- CSR fill (sorted by dst, then relation) ----------------
__global__ void k_fill(const int* __restrict__ ei, const int* __restrict__ et,
                       int* __restrict__ cursor, int* __restrict__ meta) {
  int e = blockIdx.x * blockDim.x + threadIdx.x;
  if (e >= NE) return;
  int src = ei[e], dst = ei[NE + e];
  int pos = atomicAdd(&cursor[dst * NR + et[e]], 1);
  meta[pos] = src;
}

// ---------------- edge cosine weights over sorted CSR (dst-local, bf16) ---------
__global__ void k_we2(const short* __restrict__ hb, const float* __restrict__ ninv,
                      const int* __restrict__ rp2, const int* __restrict__ meta,
                      float* __restrict__ wsort) {
  int n = blockIdx.x;
  int g = threadIdx.x >> 4, sl = threadIdx.x & 15;  // 256 threads
  int beg = rp2[n * 4], end = rp2[n * 4 + 4];
  if (beg == end) return;
  const uint4* hd = (const uint4*)(hb + (size_t)n * DD);
  uint4 b0 = hd[sl], b1 = hd[16 + sl], b2 = hd[32 + sl];
  float nd = ninv[n];
  for (int s = beg + g; s < end; s += 16) {
    int src = meta[s];
    const uint4* hs = (const uint4*)(hb + (size_t)src * DD);
    float acc = dot8(hs[sl], b0) + dot8(hs[16 + sl], b1) + dot8(hs[32 + sl], b2);
#pragma unroll
    for (int m = 8; m; m >>= 1) acc += __shfl_xor(acc, m, 64);
    if (sl == 0) wsort[s] = acc * ninv[src] * nd;
  }
}

// ---------------- per-relation aggregation of h (fp8 gather), 4-deep unroll ------
// fp8 table = 3.1MB: fits per-XCD L2; halves gather bytes vs bf16.
__global__ void k_aggrel(const unsigned char* __restrict__ f8, const int* __restrict__ rp2,
                         const int* __restrict__ meta, const float* __restrict__ wsort,
                         const float* __restrict__ nc, short* __restrict__ Agg,
                         float* __restrict__ SC, int layer) {
  int n = blockIdx.x;
  int t = threadIdx.x;       // 384
  int r = t / 96;            // relation group
  int i = t - r * 96;        // 0..95, owns cols [4i, 4i+4)
  int beg = rp2[n * 4 + r], end = rp2[n * 4 + r + 1];
  float a0 = 0, a1 = 0, a2 = 0, a3 = 0, s = 0;
  int e = beg;
  for (; e + 3 < end; e += 4) {
    int s0 = meta[e], s1 = meta[e + 1], s2 = meta[e + 2], s3 = meta[e + 3];
    float w0 = wsort[e], w1 = wsort[e + 1], w2 = wsort[e + 2], w3 = wsort[e + 3];
    unsigned u0 = ((const unsigned*)(f8 + (size_t)s0 * DD))[i];
    unsigned u1 = ((const unsigned*)(f8 + (size_t)s1 * DD))[i];
    unsigned u2 = ((const unsigned*)(f8 + (size_t)s2 * DD))[i];
    unsigned u3 = ((const unsigned*)(f8 + (size_t)s3 * DD))[i];
    a0 += w0 * f8b(u0, 0) + w1 * f8b(u1, 0) + w2 * f8b(u2, 0) + w3 * f8b(u3, 0);
    a1 += w0 * f8b(u0, 1) + w1 * f8b(u1, 1) + w2 * f8b(u2, 1) + w3 * f8b(u3, 1);
    a2 += w0 * f8b(u0, 2) + w1 * f8b(u1, 2) + w2 * f8b(u2, 2) + w3 * f8b(u3, 2);
    a3 += w0 * f8b(u0, 3) + w1 * f8b(u1, 3) + w2 * f8b(u2, 3) + w3 * f8b(u3, 3);
    s += w0 + w1 + w2 + w3;
  }
  for (; e < end; ++e) {
    int s0 = meta[e];
    float w0 = wsort[e];
    unsigned u0 = ((const unsigned*)(f8 + (size_t)s0 * DD))[i];
    a0 += w0 * f8b(u0, 0); a1 += w0 * f8b(u0, 1);
    a2 += w0 * f8b(u0, 2); a3 += w0 * f8b(u0, 3);
    s += w0;
  }
  int c = end - beg;
  float f = 1.f / (nc[layer * 4 + r] * (float)(c > 1 ? c : 1));
  uint2 o;
  o.x = pack_bf2(a0 * f, a1 * f);
  o.y = pack_bf2(a2 * f, a3 * f);
  ((uint2*)(Agg + (size_t)n * 1536 + r * 384))[i] = o;
  if (i == 0) SC[n * 4 + r] = s * f;
}

// ---------------- MP mean aggregation of rel_out (bf16), 4-deep unroll ------------
__global__ void k_aggmp(short* __restrict__ B1, const int* __restrict__ rp2,
                        const int* __restrict__ meta) {
  __shared__ float red[3][96][4];
  int n = blockIdx.x;
  int t = threadIdx.x;  // 384
  int g = t / 96, i = t - g * 96;
  int beg = rp2[n * 4], end = rp2[n * 4 + 4];
  float a0 = 0, a1 = 0, a2 = 0, a3 = 0;
  int e = beg + g;
  for (; e + 12 < end; e += 16) {
    int s0 = meta[e], s1 = meta[e + 4], s2 = meta[e + 8], s3 = meta[e + 12];
    uint2 u0 = ((const uint2*)(B1 + (size_t)s0 * 768 + 384))[i];
    uint2 u1 = ((const uint2*)(B1 + (size_t)s1 * 768 + 384))[i];
    uint2 u2 = ((const uint2*)(B1 + (size_t)s2 * 768 + 384))[i];
    uint2 u3 = ((const uint2*)(B1 + (size_t)s3 * 768 + 384))[i];
    a0 += bflo(u0.x) + bflo(u1.x) + bflo(u2.x) + bflo(u3.x);
    a1 += bfhi(u0.x) + bfhi(u1.x) + bfhi(u2.x) + bfhi(u3.x);
    a2 += bflo(u0.y) + bflo(u1.y) + bflo(u2.y) + bflo(u3.y);
    a3 += bfhi(u0.y) + bfhi(u1.y) + bfhi(u2.y) + bfhi(u3.y);
  }
  for (; e < end; e += 4) {
    int s0 = meta[e];
    uint2 u = ((const uint2*)(B1 + (size_t)s0 * 768 + 384))[i];
    a0 += bflo(u.x); a1 += bfhi(u.x);
    a2 += bflo(u.y); a3 += bfhi(u.y);
  }
  if (g) {
    red[g - 1][i][0] = a0; red[g - 1][i][1] = a1;
    red[g - 1][i][2] = a2; red[g - 1][i][3] = a3;
  }
  __syncthreads();
  if (g == 0) {
#pragma unroll
    for (int k = 0; k < 3; ++k) {
      a0 += red[k][i][0]; a1 += red[k][i][1];
      a2 += red[k][i][2]; a3 += red[k][i][3];
    }
    float inv = (end > beg) ? 1.f / (float)(end - beg) : 0.f;
    uint2 o;
    o.x = pack_bf2(a0 * inv, a1 * inv);
    o.y = pack_bf2(a2 * inv, a3 * inv);
    ((uint2*)(B1 + (size_t)n * 768))[i] = o;
  }
}

// ---------------- bf16 MFMA NT GEMM, double-buffered, XCD-chunked grid -----------
// 64x64 tile, 4 waves (each 32x32), BK=64, global_load_lds w=16, XOR-swizzled LDS.
// 1-D grid 768: wg=(bid&7)*96+(bid>>3); bm=wg/6, bn=wg%6.
// NOTE: 128^2 tile measured WORSE here (r11: 56us, 7% occ) — skinny-N shape needs
// the 768-block 64^2 grid.
// MODE 0: C = relu(acc + sum_r SC[row][r]*b_rel[r][col]) -> bf16 B1[:,384:768]
// MODE 1: h = relu(acc + deg?b_msg + b_self) + h (fp32), also h_f8 = fp8(h)
template <int MODE>
__global__ __launch_bounds__(256) void k_gemm_mfma(
    const short* __restrict__ A, int K, const short* __restrict__ Bp,
    const float* __restrict__ SC, const float* __restrict__ brel_l,
    const float* __restrict__ bmsg_l, const float* __restrict__ bself_l,
    const int* __restrict__ rp2, float* __restrict__ h,
    unsigned char* __restrict__ h_f8, short* __restrict__ Cout) {
  __shared__ short As[2][64 * 64];   // 8KB per buffer: 64 rows x 8 chunks(16B)
  __shared__ short Bs[2][64 * 64];   // chunk q' of row r holds global chunk q'^(r&7)
  int tid = threadIdx.x;
  int lane = tid & 63;
  int w = tid >> 6;              // 0..3
  int wr = w >> 1, wc = w & 1;   // wave tile origin (wr*32, wc*32)
  int bid = blockIdx.x;          // 768
  int wg = ((bid & 7) * 96) + (bid >> 3);
  int bm = wg / 6, bn = wg - bm * 6;

  int r0 = (w << 3) + (lane >> 3);        // rows 0..31 (set 0); set 1 adds 32
  int qg = (lane & 7) ^ (r0 & 7);         // (r0+32)&7 == r0&7
  const short* Ag0 = A + (size_t)(bm * 64 + r0) * K + qg * 8;
  const short* Ag1 = A + (size_t)(bm * 64 + r0 + 32) * K + qg * 8;
  const short* Bg0 = Bp + (size_t)(bn * 64 + r0) * K + qg * 8;
  const short* Bg1 = Bp + (size_t)(bn * 64 + r0 + 32) * K + qg * 8;

  auto stage = [&](int bi, int k0) {
    gl_lds16(Ag0 + k0, &As[bi][w * 512]);
    gl_lds16(Ag1 + k0, &As[bi][2048 + w * 512]);
    gl_lds16(Bg0 + k0, &Bs[bi][w * 512]);
    gl_lds16(Bg1 + k0, &Bs[bi][2048 + w * 512]);
  };

  f32x4 acc[2][2] = {};
  int fr = lane & 15, fq = lane >> 4;
  int nt = K >> 6;
  stage(0, 0);
  __syncthreads();
  for (int t = 0; t < nt; ++t) {
    if (t + 1 < nt) stage((t + 1) & 1, (t + 1) << 6);
    const short* Ab = As[t & 1];
    const short* Bb = Bs[t & 1];
#pragma unroll
    for (int kk = 0; kk < 2; ++kk) {
      bf16x8 a[2], b[2];
#pragma unroll
      for (int i = 0; i < 2; ++i) {
        int r = wr * 32 + i * 16 + fr;
        int qs = (kk * 4 + fq) ^ (r & 7);
        a[i] = *(const bf16x8*)&Ab[r * 64 + qs * 8];
      }
#pragma unroll
      for (int j = 0; j < 2; ++j) {
        int r = wc * 32 + j * 16 + fr;
        int qs = (kk * 4 + fq) ^ (r & 7);
        b[j] = *(const bf16x8*)&Bb[r * 64 + qs * 8];
      }
#pragma unroll
      for (int i = 0; i < 2; ++i)
#pragma unroll
        for (int j = 0; j < 2; ++j)
          acc[i][j] = __builtin_amdgcn_mfma_f32_16x16x32_bf16(a[i], b[j], acc[i][j], 0, 0, 0);
    }
    __syncthreads();
  }

  int cr = (lane >> 4) * 4;
  int cc = lane & 15;
#pragma unroll
  for (int i = 0; i < 2; ++i) {
#pragma unroll
    for (int jj = 0; jj < 4; ++jj) {
      int row = bm * 64 + wr * 32 + i * 16 + cr + jj;
      if (MODE == 0) {
        float4 sc = *(const float4*)&SC[row * 4];
#pragma unroll
        for (int j = 0; j < 2; ++j) {
          int col = bn * 64 + wc * 32 + j * 16 + cc;
          float v = acc[i][j][jj] + sc.x * brel_l[col] + sc.y * brel_l[384 + col] +
                    sc.z * brel_l[768 + col] + sc.w * brel_l[1152 + col];
          Cout[(size_t)row * 768 + 384 + col] = (short)f2bf(fmaxf(v, 0.f));
        }
      } else {
        float bmul = (rp2[(row + 1) * 4] > rp2[row * 4]) ? 1.f : 0.f;
#pragma unroll
        for (int j = 0; j < 2; ++j) {
          int col = bn * 64 + wc * 32 + j * 16 + cc;
          float v = acc[i][j][jj] + bmul * bmsg_l[col] + bself_l[col];
          float o = fmaxf(v, 0.f) + h[(size_t)row * DD + col];
          h[(size_t)row * DD + col] = o;
          h_f8[(size_t)row * DD + col] = f2f8(o);
        }
      }
    }
  }
}

// ---------------- final per-batch mean ----------------
__global__ void k_out(const float* __restrict__ h, float* __restrict__ out) {
  int b = blockIdx.x;   // 64
  int c = threadIdx.x;  // 384
  float s = 0.f;
  for (int j = 0; j < 128; ++j) s += h[(size_t)(b * 128 + j) * DD + c];
  out[b * DD + c] = s * (1.f / 128.f);
}

extern "C" void kernel_launch(void* const* d_in, const int* in_sizes, int n_in,
                              void* d_out, int out_size, void* d_ws, size_t ws_size,
                              hipStream_t stream) {
  const float* x      = (const float*)d_in[0];
  const int*   ei     = (const int*)d_in[1];
  const int*   et     = (const int*)d_in[2];
  const float* gamma  = (const float*)d_in[3];
  const float* beta   = (const float*)d_in[4];
  const float* W_rel  = (const float*)d_in[5];
  const float* b_rel  = (const float*)d_in[6];
  const float* nc     = (const float*)d_in[7];
  const float* W_msg  = (const float*)d_in[8];
  const float* b_msg  = (const float*)d_in[9];
  const float* W_self = (const float*)d_in[10];
  const float* b_self = (const float*)d_in[11];
  float* out = (float*)d_out;

  char* ws = (char*)d_ws;
  size_t off = 0;
  auto alloc = [&](size_t bytes) -> void* {
    void* p = ws + off;
    off = (off + bytes + 255) & ~(size_t)255;
    return p;
  };
  float* h      = (float*)alloc((size_t)NN * DD * 4);
  short* h_bf   = (short*)alloc((size_t)NN * DD * 2);
  unsigned char* h_f8 = (unsigned char*)alloc((size_t)NN * DD);
  short* Agg    = (short*)alloc((size_t)NN * 1536 * 2);
  short* B1     = (short*)alloc((size_t)NN * 768 * 2);
  short* Wcat   = (short*)alloc((size_t)NL * 384 * 1536 * 2);
  short* Wcat2  = (short*)alloc((size_t)NL * 384 * 768 * 2);
  float* SC     = (float*)alloc((size_t)NN * 4 * 4);
  int*   meta   = (int*)alloc((size_t)NE * 4);
  float* wsort  = (float*)alloc((size_t)NE * 4);
  int*   rp2    = (int*)alloc((size_t)(NN * 4 + 1) * 4);
  int*   cursor = (int*)alloc((size_t)NN * 4 * 4);
  float* ninv   = (float*)alloc((size_t)NN * 4);
  char*  zb     = (char*)alloc(134144);  // musum|msqsum|c_rel contiguous, zeroed
  float* musum  = (float*)(zb);
  float* msqsum = (float*)(zb + 1536);
  int*   c_rel  = (int*)(zb + 3072);

  k_zero<<<(134144 / 16 + 255) / 256, 256, 0, stream>>>((uint4*)zb, 134144 / 16);
  k_pre<<<5547, 384, 0, stream>>>(x, musum, msqsum, ei, et, c_rel,
                                  W_rel, W_msg, W_self, Wcat, Wcat2);
  k_bn<<<NN, 64, 0, stream>>>(x, gamma, beta, musum, msqsum, h, h_bf, h_f8, ninv);
  k_scan<<<1, 1024, 0, stream>>>(c_rel, rp2, cursor);
  k_fill<<<NE / 256, 256, 0, stream>>>(ei, et, cursor, meta);
  k_we2<<<NN, 256, 0, stream>>>(h_bf, ninv, rp2, meta, wsort);

  for (int l = 0; l < NL; ++l) {
    k_aggrel<<<NN, 384, 0, stream>>>(h_f8, rp2, meta, wsort, nc, Agg, SC, l);
    k_gemm_mfma<0><<<768, 256, 0, stream>>>(
        Agg, 1536, Wcat + (size_t)l * 384 * 1536, SC, b_rel + l * NR * DD,
        nullptr, nullptr, nullptr, nullptr, nullptr, B1);
    k_aggmp<<<NN, 384, 0, stream>>>(B1, rp2, meta);
    k_gemm_mfma<1><<<768, 256, 0, stream>>>(
        B1, 768, Wcat2 + (size_t)l * 384 * 768, nullptr, nullptr,
        b_msg + l * DD, b_self + l * DD, rp2, h, h_f8, nullptr);
  }
  k_out<<<64, 384, 0, stream>>>(h, out);
}

// Round 15
// 277.923 us; speedup vs baseline: 1.4238x; 1.0299x over previous
//
#include <hip/hip_runtime.h>
#include <hip/hip_bf16.h>
#include <hip/hip_fp8.h>

#define NN 8192
#define DD 384
#define NE 262144
#define NR 4
#define NL 2
#define NB 64

typedef __attribute__((ext_vector_type(8))) short bf16x8;
typedef __attribute__((ext_vector_type(4))) float f32x4;

__device__ __forceinline__ unsigned short f2bf(float f) {
  unsigned u = __float_as_uint(f);
  unsigned r = (u + 0x7fffu + ((u >> 16) & 1u)) >> 16;
  return (unsigned short)r;
}
__device__ __forceinline__ unsigned pack_bf2(float lo, float hi) {
  return (unsigned)f2bf(lo) | ((unsigned)f2bf(hi) << 16);
}
__device__ __forceinline__ float bflo(unsigned u) { return __uint_as_float(u << 16); }
__device__ __forceinline__ float bfhi(unsigned u) { return __uint_as_float(u & 0xffff0000u); }
__device__ __forceinline__ unsigned char f2f8(float f) {
  __hip_fp8_e4m3 v(f);
  return (unsigned char)v.__x;
}
__device__ __forceinline__ float f8b(unsigned u, int b) {
  __hip_fp8_e4m3 v;
  v.__x = (__hip_fp8_storage_t)((u >> (b * 8)) & 0xffu);
  return (float)v;
}
__device__ __forceinline__ void gl_lds16(const void* g, void* l) {
  __builtin_amdgcn_global_load_lds(
      (const __attribute__((address_space(1))) unsigned int*)g,
      (__attribute__((address_space(3))) unsigned int*)l, 16, 0, 0);
}
__device__ __forceinline__ float dot8(uint4 a, uint4 b) {
  return bflo(a.x) * bflo(b.x) + bfhi(a.x) * bfhi(b.x) +
         bflo(a.y) * bflo(b.y) + bfhi(a.y) * bfhi(b.y) +
         bflo(a.z) * bflo(b.z) + bfhi(a.z) * bfhi(b.z) +
         bflo(a.w) * bflo(b.w) + bfhi(a.w) * bfhi(b.w);
}

// ---------------- workspace zeroing ----------------
__global__ void k_zero(uint4* __restrict__ p, int n4) {
  int i = blockIdx.x * 256 + threadIdx.x;
  if (i < n4) p[i] = make_uint4(0, 0, 0, 0);
}

// ---------------- fused prologue: colstats | counts | packall ----------------
__global__ void k_pre(const float* __restrict__ x, float* __restrict__ musum,
                      float* __restrict__ msqsum, const int* __restrict__ ei,
                      const int* __restrict__ et, int* __restrict__ c_rel,
                      const float* __restrict__ W_rel, const float* __restrict__ W_msg,
                      const float* __restrict__ W_self, short* __restrict__ Wcat,
                      short* __restrict__ Wcat2) {
  int b = blockIdx.x;
  int t = threadIdx.x;
  if (b < 256) {
    int c = t;                 // 384
    int r0 = b * 32;
    float s = 0.f, s2 = 0.f;
    for (int r = 0; r < 32; ++r) {
      float v = x[(size_t)(r0 + r) * DD + c];
      s += v; s2 += v * v;
    }
    atomicAdd(&musum[c], s);
    atomicAdd(&msqsum[c], s2);
  } else if (b < 939) {
    int e = (b - 256) * 384 + t;
    if (e < NE) {
      int dst = ei[NE + e];
      atomicAdd(&c_rel[dst * NR + et[e]], 1);
    }
  } else {
    const int T1 = NL * 384 * 1536;
    int idx = (b - 939) * 384 + t;
    if (idx < T1) {
      int l = idx / (384 * 1536);
      int rem = idx - l * 384 * 1536;
      int i = rem / 1536, kk = rem - i * 1536;
      int r = kk / 384, k = kk - r * 384;
      Wcat[idx] = (short)f2bf(W_rel[(((size_t)(l * NR + r) * DD) + i) * DD + k]);
    } else {
      int j = idx - T1;
      int l = j / (384 * 768);
      int rem = j - l * 384 * 768;
      int i = rem / 768, kk = rem - i * 768;
      float v = (kk < 384) ? W_msg[((size_t)l * DD + i) * DD + kk]
                           : W_self[((size_t)l * DD + i) * DD + kk - 384];
      Wcat2[j] = (short)f2bf(v);
    }
  }
}

// h = gamma*(x-mu)*rstd + beta ; ninv = 1/||h||_row ; h_bf = bf16(h); h_f8 = fp8(h)
__global__ void k_bn(const float* __restrict__ x, const float* __restrict__ gamma,
                     const float* __restrict__ beta, const float* __restrict__ musum,
                     const float* __restrict__ msqsum, float* __restrict__ h,
                     short* __restrict__ h_bf, unsigned char* __restrict__ h_f8,
                     float* __restrict__ ninv) {
  int n = blockIdx.x;
  int t = threadIdx.x;  // 64
  float ss = 0.f;
#pragma unroll
  for (int i = 0; i < 6; ++i) {
    int c = t + i * 64;
    float m = musum[c] * (1.f / NN);
    float var = msqsum[c] * (1.f / NN) - m * m;
    float v = gamma[c] * (x[(size_t)n * DD + c] - m) * rsqrtf(var + 1e-5f) + beta[c];
    h[(size_t)n * DD + c] = v;
    h_bf[(size_t)n * DD + c] = (short)f2bf(v);
    h_f8[(size_t)n * DD + c] = f2f8(v);
    ss += v * v;
  }
#pragma unroll
  for (int m = 32; m; m >>= 1) ss += __shfl_xor(ss, m, 64);
  if (t == 0) ninv[n] = rsqrtf(ss);
}

// exclusive scan of c_rel (32768) -> rp2[32769], cursor copy
__global__ void k_scan(const int* __restrict__ c_rel, int* __restrict__ rp2,
                       int* __restrict__ cursor) {
  __shared__ int part[1024];
  int t = threadIdx.x;
  int base = t * 32;
  int v[32]; int s = 0;
#pragma unroll
  for (int i = 0; i < 32; ++i) { v[i] = c_rel[base + i]; s += v[i]; }
  part[t] = s;
  __syncthreads();
  for (int off = 1; off < 1024; off <<= 1) {
    int add = (t >= off) ? part[t - off] : 0;
    __syncthreads();
    part[t] += add;
    __syncthreads();
  }
  int run = (t == 0) ? 0 : part[t - 1];
  if (t == 0) rp2[0] = 0;
#pragma unroll
  for (int i = 0; i < 32; ++i) {
    cursor[base + i] = run;
    run += v[i];
    rp2[base + i + 1] = run;
  }
}

// ---------------- CSR fill (sorted by dst, then relation) ----------------
__global__ void k_fill(const int* __restrict__ ei, const int* __restrict__ et,
                       int* __restrict__ cursor, int* __restrict__ meta) {
  int e = blockIdx.x * blockDim.x + threadIdx.x;
  if (e >= NE) return;
  int src = ei[e], dst = ei[NE + e];
  int pos = atomicAdd(&cursor[dst * NR + et[e]], 1);
  meta[pos] = src;
}

// ---------------- edge cosine weights over sorted CSR (dst-local, bf16) ---------
__global__ void k_we2(const short* __restrict__ hb, const float* __restrict__ ninv,
                      const int* __restrict__ rp2, const int* __restrict__ meta,
                      float* __restrict__ wsort) {
  int n = blockIdx.x;
  int g = threadIdx.x >> 4, sl = threadIdx.x & 15;  // 256 threads
  int beg = rp2[n * 4], end = rp2[n * 4 + 4];
  if (beg == end) return;
  const uint4* hd = (const uint4*)(hb + (size_t)n * DD);
  uint4 b0 = hd[sl], b1 = hd[16 + sl], b2 = hd[32 + sl];
  float nd = ninv[n];
  for (int s = beg + g; s < end; s += 16) {
    int src = meta[s];
    const uint4* hs = (const uint4*)(hb + (size_t)src * DD);
    float acc = dot8(hs[sl], b0) + dot8(hs[16 + sl], b1) + dot8(hs[32 + sl], b2);
#pragma unroll
    for (int m = 8; m; m >>= 1) acc += __shfl_xor(acc, m, 64);
    if (sl == 0) wsort[s] = acc * ninv[src] * nd;
  }
}

// ---------------- per-relation aggregation of h (fp8 gather), 4-deep unroll ------
// fp8 table = 3.1MB: fits per-XCD L2; halves gather bytes vs bf16.
__global__ void k_aggrel(const unsigned char* __restrict__ f8, const int* __restrict__ rp2,
                         const int* __restrict__ meta, const float* __restrict__ wsort,
                         const float* __restrict__ nc, short* __restrict__ Agg,
                         float* __restrict__ SC, int layer) {
  int n = blockIdx.x;
  int t = threadIdx.x;       // 384
  int r = t / 96;            // relation group
  int i = t - r * 96;        // 0..95, owns cols [4i, 4i+4)
  int beg = rp2[n * 4 + r], end = rp2[n * 4 + r + 1];
  float a0 = 0, a1 = 0, a2 = 0, a3 = 0, s = 0;
  int e = beg;
  for (; e + 3 < end; e += 4) {
    int s0 = meta[e], s1 = meta[e + 1], s2 = meta[e + 2], s3 = meta[e + 3];
    float w0 = wsort[e], w1 = wsort[e + 1], w2 = wsort[e + 2], w3 = wsort[e + 3];
    unsigned u0 = ((const unsigned*)(f8 + (size_t)s0 * DD))[i];
    unsigned u1 = ((const unsigned*)(f8 + (size_t)s1 * DD))[i];
    unsigned u2 = ((const unsigned*)(f8 + (size_t)s2 * DD))[i];
    unsigned u3 = ((const unsigned*)(f8 + (size_t)s3 * DD))[i];
    a0 += w0 * f8b(u0, 0) + w1 * f8b(u1, 0) + w2 * f8b(u2, 0) + w3 * f8b(u3, 0);
    a1 += w0 * f8b(u0, 1) + w1 * f8b(u1, 1) + w2 * f8b(u2, 1) + w3 * f8b(u3, 1);
    a2 += w0 * f8b(u0, 2) + w1 * f8b(u1, 2) + w2 * f8b(u2, 2) + w3 * f8b(u3, 2);
    a3 += w0 * f8b(u0, 3) + w1 * f8b(u1, 3) + w2 * f8b(u2, 3) + w3 * f8b(u3, 3);
    s += w0 + w1 + w2 + w3;
  }
  for (; e < end; ++e) {
    int s0 = meta[e];
    float w0 = wsort[e];
    unsigned u0 = ((const unsigned*)(f8 + (size_t)s0 * DD))[i];
    a0 += w0 * f8b(u0, 0); a1 += w0 * f8b(u0, 1);
    a2 += w0 * f8b(u0, 2); a3 += w0 * f8b(u0, 3);
    s += w0;
  }
  int c = end - beg;
  float f = 1.f / (nc[layer * 4 + r] * (float)(c > 1 ? c : 1));
  uint2 o;
  o.x = pack_bf2(a0 * f, a1 * f);
  o.y = pack_bf2(a2 * f, a3 * f);
  ((uint2*)(Agg + (size_t)n * 1536 + r * 384))[i] = o;
  if (i == 0) SC[n * 4 + r] = s * f;
}

// ---------------- MP mean aggregation of rel_out (fp8 gather), 4-deep unroll ------
// rel8 table = 3.1MB compact fp8: fits per-XCD L2; halves gather bytes.
// Writes bf16 B1[:,0:384] (A operand of gemm<1>).
__global__ void k_aggmp(short* __restrict__ B1, const unsigned char* __restrict__ rel8,
                        const int* __restrict__ rp2, const int* __restrict__ meta) {
  __shared__ float red[3][96][4];
  int n = blockIdx.x;
  int t = threadIdx.x;  // 384
  int g = t / 96, i = t - g * 96;
  int beg = rp2[n * 4], end = rp2[n * 4 + 4];
  float a0 = 0, a1 = 0, a2 = 0, a3 = 0;
  int e = beg + g;
  for (; e + 12 < end; e += 16) {
    int s0 = meta[e], s1 = meta[e + 4], s2 = meta[e + 8], s3 = meta[e + 12];
    unsigned u0 = ((const unsigned*)(rel8 + (size_t)s0 * DD))[i];
    unsigned u1 = ((const unsigned*)(rel8 + (size_t)s1 * DD))[i];
    unsigned u2 = ((const unsigned*)(rel8 + (size_t)s2 * DD))[i];
    unsigned u3 = ((const unsigned*)(rel8 + (size_t)s3 * DD))[i];
    a0 += f8b(u0, 0) + f8b(u1, 0) + f8b(u2, 0) + f8b(u3, 0);
    a1 += f8b(u0, 1) + f8b(u1, 1) + f8b(u2, 1) + f8b(u3, 1);
    a2 += f8b(u0, 2) + f8b(u1, 2) + f8b(u2, 2) + f8b(u3, 2);
    a3 += f8b(u0, 3) + f8b(u1, 3) + f8b(u2, 3) + f8b(u3, 3);
  }
  for (; e < end; e += 4) {
    int s0 = meta[e];
    unsigned u = ((const unsigned*)(rel8 + (size_t)s0 * DD))[i];
    a0 += f8b(u, 0); a1 += f8b(u, 1);
    a2 += f8b(u, 2); a3 += f8b(u, 3);
  }
  if (g) {
    red[g - 1][i][0] = a0; red[g - 1][i][1] = a1;
    red[g - 1][i][2] = a2; red[g - 1][i][3] = a3;
  }
  __syncthreads();
  if (g == 0) {
#pragma unroll
    for (int k = 0; k < 3; ++k) {
      a0 += red[k][i][0]; a1 += red[k][i][1];
      a2 += red[k][i][2]; a3 += red[k][i][3];
    }
    float inv = (end > beg) ? 1.f / (float)(end - beg) : 0.f;
    uint2 o;
    o.x = pack_bf2(a0 * inv, a1 * inv);
    o.y = pack_bf2(a2 * inv, a3 * inv);
    ((uint2*)(B1 + (size_t)n * 768))[i] = o;
  }
}

// ---------------- bf16 MFMA NT GEMM, double-buffered, XCD-chunked grid -----------
// 64x64 tile, 4 waves (each 32x32), BK=64, global_load_lds w=16, XOR-swizzled LDS.
// 1-D grid 768: wg=(bid&7)*96+(bid>>3); bm=wg/6, bn=wg%6.
// NOTE: 128^2 tile measured WORSE here (r11: 56us, 7% occ) — skinny-N shape needs
// the 768-block 64^2 grid.
// MODE 0: C = relu(acc + sum_r SC[row][r]*b_rel[r][col]) -> bf16 B1[:,384:768] + fp8 rel8
// MODE 1: h = relu(acc + deg?b_msg + b_self) + h (fp32), also h_f8 = fp8(h)
template <int MODE>
__global__ __launch_bounds__(256) void k_gemm_mfma(
    const short* __restrict__ A, int K, const short* __restrict__ Bp,
    const float* __restrict__ SC, const float* __restrict__ brel_l,
    const float* __restrict__ bmsg_l, const float* __restrict__ bself_l,
    const int* __restrict__ rp2, float* __restrict__ h,
    unsigned char* __restrict__ f8out, short* __restrict__ Cout) {
  __shared__ short As[2][64 * 64];   // 8KB per buffer: 64 rows x 8 chunks(16B)
  __shared__ short Bs[2][64 * 64];   // chunk q' of row r holds global chunk q'^(r&7)
  int tid = threadIdx.x;
  int lane = tid & 63;
  int w = tid >> 6;              // 0..3
  int wr = w >> 1, wc = w & 1;   // wave tile origin (wr*32, wc*32)
  int bid = blockIdx.x;          // 768
  int wg = ((bid & 7) * 96) + (bid >> 3);
  int bm = wg / 6, bn = wg - bm * 6;

  int r0 = (w << 3) + (lane >> 3);        // rows 0..31 (set 0); set 1 adds 32
  int qg = (lane & 7) ^ (r0 & 7);         // (r0+32)&7 == r0&7
  const short* Ag0 = A + (size_t)(bm * 64 + r0) * K + qg * 8;
  const short* Ag1 = A + (size_t)(bm * 64 + r0 + 32) * K + qg * 8;
  const short* Bg0 = Bp + (size_t)(bn * 64 + r0) * K + qg * 8;
  const short* Bg1 = Bp + (size_t)(bn * 64 + r0 + 32) * K + qg * 8;

  auto stage = [&](int bi, int k0) {
    gl_lds16(Ag0 + k0, &As[bi][w * 512]);
    gl_lds16(Ag1 + k0, &As[bi][2048 + w * 512]);
    gl_lds16(Bg0 + k0, &Bs[bi][w * 512]);
    gl_lds16(Bg1 + k0, &Bs[bi][2048 + w * 512]);
  };

  f32x4 acc[2][2] = {};
  int fr = lane & 15, fq = lane >> 4;
  int nt = K >> 6;
  stage(0, 0);
  __syncthreads();
  for (int t = 0; t < nt; ++t) {
    if (t + 1 < nt) stage((t + 1) & 1, (t + 1) << 6);
    const short* Ab = As[t & 1];
    const short* Bb = Bs[t & 1];
#pragma unroll
    for (int kk = 0; kk < 2; ++kk) {
      bf16x8 a[2], b[2];
#pragma unroll
      for (int i = 0; i < 2; ++i) {
        int r = wr * 32 + i * 16 + fr;
        int qs = (kk * 4 + fq) ^ (r & 7);
        a[i] = *(const bf16x8*)&Ab[r * 64 + qs * 8];
      }
#pragma unroll
      for (int j = 0; j < 2; ++j) {
        int r = wc * 32 + j * 16 + fr;
        int qs = (kk * 4 + fq) ^ (r & 7);
        b[j] = *(const bf16x8*)&Bb[r * 64 + qs * 8];
      }
#pragma unroll
      for (int i = 0; i < 2; ++i)
#pragma unroll
        for (int j = 0; j < 2; ++j)
          acc[i][j] = __builtin_amdgcn_mfma_f32_16x16x32_bf16(a[i], b[j], acc[i][j], 0, 0, 0);
    }
    __syncthreads();
  }

  int cr = (lane >> 4) * 4;
  int cc = lane & 15;
#pragma unroll
  for (int i = 0; i < 2; ++i) {
#pragma unroll
    for (int jj = 0; jj < 4; ++jj) {
      int row = bm * 64 + wr * 32 + i * 16 + cr + jj;
      if (MODE == 0) {
        float4 sc = *(const float4*)&SC[row * 4];
#pragma unroll
        for (int j = 0; j < 2; ++j) {
          int col = bn * 64 + wc * 32 + j * 16 + cc;
          float v = acc[i][j][jj] + sc.x * brel_l[col] + sc.y * brel_l[384 + col] +
                    sc.z * brel_l[768 + col] + sc.w * brel_l[1152 + col];
          float rl = fmaxf(v, 0.f);
          Cout[(size_t)row * 768 + 384 + col] = (short)f2bf(rl);
          f8out[(size_t)row * DD + col] = f2f8(rl);
        }
      } else {
        float bmul = (rp2[(row + 1) * 4] > rp2[row * 4]) ? 1.f : 0.f;
#pragma unroll
        for (int j = 0; j < 2; ++j) {
          int col = bn * 64 + wc * 32 + j * 16 + cc;
          float v = acc[i][j][jj] + bmul * bmsg_l[col] + bself_l[col];
          float o = fmaxf(v, 0.f) + h[(size_t)row * DD + col];
          h[(size_t)row * DD + col] = o;
          f8out[(size_t)row * DD + col] = f2f8(o);
        }
      }
    }
  }
}

// ---------------- final per-batch mean ----------------
__global__ void k_out(const float* __restrict__ h, float* __restrict__ out) {
  int b = blockIdx.x;   // 64
  int c = threadIdx.x;  // 384
  float s = 0.f;
  for (int j = 0; j < 128; ++j) s += h[(size_t)(b * 128 + j) * DD + c];
  out[b * DD + c] = s * (1.f / 128.f);
}

extern "C" void kernel_launch(void* const* d_in, const int* in_sizes, int n_in,
                              void* d_out, int out_size, void* d_ws, size_t ws_size,
                              hipStream_t stream) {
  const float* x      = (const float*)d_in[0];
  const int*   ei     = (const int*)d_in[1];
  const int*   et     = (const int*)d_in[2];
  const float* gamma  = (const float*)d_in[3];
  const float* beta   = (const float*)d_in[4];
  const float* W_rel  = (const float*)d_in[5];
  const float* b_rel  = (const float*)d_in[6];
  const float* nc     = (const float*)d_in[7];
  const float* W_msg  = (const float*)d_in[8];
  const float* b_msg  = (const float*)d_in[9];
  const float* W_self = (const float*)d_in[10];
  const float* b_self = (const float*)d_in[11];
  float* out = (float*)d_out;

  char* ws = (char*)d_ws;
  size_t off = 0;
  auto alloc = [&](size_t bytes) -> void* {
    void* p = ws + off;
    off = (off + bytes + 255) & ~(size_t)255;
    return p;
  };
  float* h      = (float*)alloc((size_t)NN * DD * 4);
  short* h_bf   = (short*)alloc((size_t)NN * DD * 2);
  unsigned char* h_f8 = (unsigned char*)alloc((size_t)NN * DD);
  unsigned char* rel8 = (unsigned char*)alloc((size_t)NN * DD);
  short* Agg    = (short*)alloc((size_t)NN * 1536 * 2);
  short* B1     = (short*)alloc((size_t)NN * 768 * 2);
  short* Wcat   = (short*)alloc((size_t)NL * 384 * 1536 * 2);
  short* Wcat2  = (short*)alloc((size_t)NL * 384 * 768 * 2);
  float* SC     = (float*)alloc((size_t)NN * 4 * 4);
  int*   meta   = (int*)alloc((size_t)NE * 4);
  float* wsort  = (float*)alloc((size_t)NE * 4);
  int*   rp2    = (int*)alloc((size_t)(NN * 4 + 1) * 4);
  int*   cursor = (int*)alloc((size_t)NN * 4 * 4);
  float* ninv   = (float*)alloc((size_t)NN * 4);
  char*  zb     = (char*)alloc(134144);  // musum|msqsum|c_rel contiguous, zeroed
  float* musum  = (float*)(zb);
  float* msqsum = (float*)(zb + 1536);
  int*   c_rel  = (int*)(zb + 3072);

  k_zero<<<(134144 / 16 + 255) / 256, 256, 0, stream>>>((uint4*)zb, 134144 / 16);
  k_pre<<<5547, 384, 0, stream>>>(x, musum, msqsum, ei, et, c_rel,
                                  W_rel, W_msg, W_self, Wcat, Wcat2);
  k_bn<<<NN, 64, 0, stream>>>(x, gamma, beta, musum, msqsum, h, h_bf, h_f8, ninv);
  k_scan<<<1, 1024, 0, stream>>>(c_rel, rp2, cursor);
  k_fill<<<NE / 256, 256, 0, stream>>>(ei, et, cursor, meta);
  k_we2<<<NN, 256, 0, stream>>>(h_bf, ninv, rp2, meta, wsort);

  for (int l = 0; l < NL; ++l) {
    k_aggrel<<<NN, 384, 0, stream>>>(h_f8, rp2, meta, wsort, nc, Agg, SC, l);
    k_gemm_mfma<0><<<768, 256, 0, stream>>>(
        Agg, 1536, Wcat + (size_t)l * 384 * 1536, SC, b_rel + l * NR * DD,
        nullptr, nullptr, nullptr, nullptr, rel8, B1);
    k_aggmp<<<NN, 384, 0, stream>>>(B1, rel8, rp2, meta);
    k_gemm_mfma<1><<<768, 256, 0, stream>>>(
        B1, 768, Wcat2 + (size_t)l * 384 * 768, nullptr, nullptr,
        b_msg + l * DD, b_self + l * DD, rp2, h, h_f8, nullptr);
  }
  k_out<<<64, 384, 0, stream>>>(h, out);
}

// Round 16
// 274.392 us; speedup vs baseline: 1.4421x; 1.0129x over previous
//
#include <hip/hip_runtime.h>
#include <hip/hip_bf16.h>
#include <hip/hip_fp8.h>

#define NN 8192
#define DD 384
#define NE 262144
#define NR 4
#define NL 2
#define NB 64

typedef __attribute__((ext_vector_type(8))) short bf16x8;
typedef __attribute__((ext_vector_type(4))) float f32x4;

__device__ __forceinline__ unsigned short f2bf(float f) {
  unsigned u = __float_as_uint(f);
  unsigned r = (u + 0x7fffu + ((u >> 16) & 1u)) >> 16;
  return (unsigned short)r;
}
__device__ __forceinline__ unsigned pack_bf2(float lo, float hi) {
  return (unsigned)f2bf(lo) | ((unsigned)f2bf(hi) << 16);
}
__device__ __forceinline__ float bflo(unsigned u) { return __uint_as_float(u << 16); }
__device__ __forceinline__ float bfhi(unsigned u) { return __uint_as_float(u & 0xffff0000u); }
__device__ __forceinline__ unsigned char f2f8(float f) {
  __hip_fp8_e4m3 v(f);
  return (unsigned char)v.__x;
}
__device__ __forceinline__ float f8b(unsigned u, int b) {
  __hip_fp8_e4m3 v;
  v.__x = (__hip_fp8_storage_t)((u >> (b * 8)) & 0xffu);
  return (float)v;
}
__device__ __forceinline__ void gl_lds16(const void* g, void* l) {
  __builtin_amdgcn_global_load_lds(
      (const __attribute__((address_space(1))) unsigned int*)g,
      (__attribute__((address_space(3))) unsigned int*)l, 16, 0, 0);
}
__device__ __forceinline__ float dot8(uint4 a, uint4 b) {
  return bflo(a.x) * bflo(b.x) + bfhi(a.x) * bfhi(b.x) +
         bflo(a.y) * bflo(b.y) + bfhi(a.y) * bfhi(b.y) +
         bflo(a.z) * bflo(b.z) + bfhi(a.z) * bfhi(b.z) +
         bflo(a.w) * bflo(b.w) + bfhi(a.w) * bfhi(b.w);
}
// mixed dot: 8 fp8 (uint2) x 8 bf16 (uint4), same element offsets
__device__ __forceinline__ float dot8m(uint2 s, uint4 b) {
  return f8b(s.x, 0) * bflo(b.x) + f8b(s.x, 1) * bfhi(b.x) +
         f8b(s.x, 2) * bflo(b.y) + f8b(s.x, 3) * bfhi(b.y) +
         f8b(s.y, 0) * bflo(b.z) + f8b(s.y, 1) * bfhi(b.z) +
         f8b(s.y, 2) * bflo(b.w) + f8b(s.y, 3) * bfhi(b.w);
}

// ---------------- workspace zeroing ----------------
__global__ void k_zero(uint4* __restrict__ p, int n4) {
  int i = blockIdx.x * 256 + threadIdx.x;
  if (i < n4) p[i] = make_uint4(0, 0, 0, 0);
}

// ---------------- fused prologue: colstats | counts | packall ----------------
__global__ void k_pre(const float* __restrict__ x, float* __restrict__ musum,
                      float* __restrict__ msqsum, const int* __restrict__ ei,
                      const int* __restrict__ et, int* __restrict__ c_rel,
                      const float* __restrict__ W_rel, const float* __restrict__ W_msg,
                      const float* __restrict__ W_self, short* __restrict__ Wcat,
                      short* __restrict__ Wcat2) {
  int b = blockIdx.x;
  int t = threadIdx.x;
  if (b < 256) {
    int c = t;                 // 384
    int r0 = b * 32;
    float s = 0.f, s2 = 0.f;
    for (int r = 0; r < 32; ++r) {
      float v = x[(size_t)(r0 + r) * DD + c];
      s += v; s2 += v * v;
    }
    atomicAdd(&musum[c], s);
    atomicAdd(&msqsum[c], s2);
  } else if (b < 939) {
    int e = (b - 256) * 384 + t;
    if (e < NE) {
      int dst = ei[NE + e];
      atomicAdd(&c_rel[dst * NR + et[e]], 1);
    }
  } else {
    const int T1 = NL * 384 * 1536;
    int idx = (b - 939) * 384 + t;
    if (idx < T1) {
      int l = idx / (384 * 1536);
      int rem = idx - l * 384 * 1536;
      int i = rem / 1536, kk = rem - i * 1536;
      int r = kk / 384, k = kk - r * 384;
      Wcat[idx] = (short)f2bf(W_rel[(((size_t)(l * NR + r) * DD) + i) * DD + k]);
    } else {
      int j = idx - T1;
      int l = j / (384 * 768);
      int rem = j - l * 384 * 768;
      int i = rem / 768, kk = rem - i * 768;
      float v = (kk < 384) ? W_msg[((size_t)l * DD + i) * DD + kk]
                           : W_self[((size_t)l * DD + i) * DD + kk - 384];
      Wcat2[j] = (short)f2bf(v);
    }
  }
}

// h = gamma*(x-mu)*rstd + beta ; ninv = 1/||h||_row ; h_bf = bf16(h); h_f8 = fp8(h)
__global__ void k_bn(const float* __restrict__ x, const float* __restrict__ gamma,
                     const float* __restrict__ beta, const float* __restrict__ musum,
                     const float* __restrict__ msqsum, float* __restrict__ h,
                     short* __restrict__ h_bf, unsigned char* __restrict__ h_f8,
                     float* __restrict__ ninv) {
  int n = blockIdx.x;
  int t = threadIdx.x;  // 64
  float ss = 0.f;
#pragma unroll
  for (int i = 0; i < 6; ++i) {
    int c = t + i * 64;
    float m = musum[c] * (1.f / NN);
    float var = msqsum[c] * (1.f / NN) - m * m;
    float v = gamma[c] * (x[(size_t)n * DD + c] - m) * rsqrtf(var + 1e-5f) + beta[c];
    h[(size_t)n * DD + c] = v;
    h_bf[(size_t)n * DD + c] = (short)f2bf(v);
    h_f8[(size_t)n * DD + c] = f2f8(v);
    ss += v * v;
  }
#pragma unroll
  for (int m = 32; m; m >>= 1) ss += __shfl_xor(ss, m, 64);
  if (t == 0) ninv[n] = rsqrtf(ss);
}

// exclusive scan of c_rel (32768) -> rp2[32769], cursor copy
__global__ void k_scan(const int* __restrict__ c_rel, int* __restrict__ rp2,
                       int* __restrict__ cursor) {
  __shared__ int part[1024];
  int t = threadIdx.x;
  int base = t * 32;
  int v[32]; int s = 0;
#pragma unroll
  for (int i = 0; i < 32; ++i) { v[i] = c_rel[base + i]; s += v[i]; }
  part[t] = s;
  __syncthreads();
  for (int off = 1; off < 1024; off <<= 1) {
    int add = (t >= off) ? part[t - off] : 0;
    __syncthreads();
    part[t] += add;
    __syncthreads();
  }
  int run = (t == 0) ? 0 : part[t - 1];
  if (t == 0) rp2[0] = 0;
#pragma unroll
  for (int i = 0; i < 32; ++i) {
    cursor[base + i] = run;
    run += v[i];
    rp2[base + i + 1] = run;
  }
}

// ---------------- CSR fill (sorted by dst, then relation) ----------------
__global__ void k_fill(const int* __restrict__ ei, const int* __restrict__ et,
                       int* __restrict__ cursor, int* __restrict__ meta) {
  int e = blockIdx.x * blockDim.x + threadIdx.x;
  if (e >= NE) return;
  int src = ei[e], dst = ei[NE + e];
  int pos = atomicAdd(&cursor[dst * NR + et[e]], 1);
  meta[pos] = src;
}

// ---------------- edge cosine weights over sorted CSR --------------
// dst row in bf16 (block-local, L1-broadcast); src rows gathered from the
// 3.1MB fp8 table (per-XCD L2-resident, half the bytes).
__global__ void k_we2(const short* __restrict__ hb, const unsigned char* __restrict__ f8,
                      const float* __restrict__ ninv, const int* __restrict__ rp2,
                      const int* __restrict__ meta, float* __restrict__ wsort) {
  int n = blockIdx.x;
  int g = threadIdx.x >> 4, sl = threadIdx.x & 15;  // 256 threads
  int beg = rp2[n * 4], end = rp2[n * 4 + 4];
  if (beg == end) return;
  const uint4* hd = (const uint4*)(hb + (size_t)n * DD);  // 48 uint4 per row
  uint4 b0 = hd[sl], b1 = hd[16 + sl], b2 = hd[32 + sl];
  float nd = ninv[n];
  for (int s = beg + g; s < end; s += 16) {
    int src = meta[s];
    const uint2* su = (const uint2*)(f8 + (size_t)src * DD);  // 48 uint2 per row
    float acc = dot8m(su[sl], b0) + dot8m(su[16 + sl], b1) + dot8m(su[32 + sl], b2);
#pragma unroll
    for (int m = 8; m; m >>= 1) acc += __shfl_xor(acc, m, 64);
    if (sl == 0) wsort[s] = acc * ninv[src] * nd;
  }
}

// ---------------- per-relation aggregation of h (fp8 gather), 4-deep unroll ------
// fp8 table = 3.1MB: fits per-XCD L2; halves gather bytes vs bf16.
__global__ void k_aggrel(const unsigned char* __restrict__ f8, const int* __restrict__ rp2,
                         const int* __restrict__ meta, const float* __restrict__ wsort,
                         const float* __restrict__ nc, short* __restrict__ Agg,
                         float* __restrict__ SC, int layer) {
  int n = blockIdx.x;
  int t = threadIdx.x;       // 384
  int r = t / 96;            // relation group
  int i = t - r * 96;        // 0..95, owns cols [4i, 4i+4)
  int beg = rp2[n * 4 + r], end = rp2[n * 4 + r + 1];
  float a0 = 0, a1 = 0, a2 = 0, a3 = 0, s = 0;
  int e = beg;
  for (; e + 3 < end; e += 4) {
    int s0 = meta[e], s1 = meta[e + 1], s2 = meta[e + 2], s3 = meta[e + 3];
    float w0 = wsort[e], w1 = wsort[e + 1], w2 = wsort[e + 2], w3 = wsort[e + 3];
    unsigned u0 = ((const unsigned*)(f8 + (size_t)s0 * DD))[i];
    unsigned u1 = ((const unsigned*)(f8 + (size_t)s1 * DD))[i];
    unsigned u2 = ((const unsigned*)(f8 + (size_t)s2 * DD))[i];
    unsigned u3 = ((const unsigned*)(f8 + (size_t)s3 * DD))[i];
    a0 += w0 * f8b(u0, 0) + w1 * f8b(u1, 0) + w2 * f8b(u2, 0) + w3 * f8b(u3, 0);
    a1 += w0 * f8b(u0, 1) + w1 * f8b(u1, 1) + w2 * f8b(u2, 1) + w3 * f8b(u3, 1);
    a2 += w0 * f8b(u0, 2) + w1 * f8b(u1, 2) + w2 * f8b(u2, 2) + w3 * f8b(u3, 2);
    a3 += w0 * f8b(u0, 3) + w1 * f8b(u1, 3) + w2 * f8b(u2, 3) + w3 * f8b(u3, 3);
    s += w0 + w1 + w2 + w3;
  }
  for (; e < end; ++e) {
    int s0 = meta[e];
    float w0 = wsort[e];
    unsigned u0 = ((const unsigned*)(f8 + (size_t)s0 * DD))[i];
    a0 += w0 * f8b(u0, 0); a1 += w0 * f8b(u0, 1);
    a2 += w0 * f8b(u0, 2); a3 += w0 * f8b(u0, 3);
    s += w0;
  }
  int c = end - beg;
  float f = 1.f / (nc[layer * 4 + r] * (float)(c > 1 ? c : 1));
  uint2 o;
  o.x = pack_bf2(a0 * f, a1 * f);
  o.y = pack_bf2(a2 * f, a3 * f);
  ((uint2*)(Agg + (size_t)n * 1536 + r * 384))[i] = o;
  if (i == 0) SC[n * 4 + r] = s * f;
}

// ---------------- MP mean aggregation of rel_out (fp8 gather), 4-deep unroll ------
__global__ void k_aggmp(short* __restrict__ B1, const unsigned char* __restrict__ rel8,
                        const int* __restrict__ rp2, const int* __restrict__ meta) {
  __shared__ float red[3][96][4];
  int n = blockIdx.x;
  int t = threadIdx.x;  // 384
  int g = t / 96, i = t - g * 96;
  int beg = rp2[n * 4], end = rp2[n * 4 + 4];
  float a0 = 0, a1 = 0, a2 = 0, a3 = 0;
  int e = beg + g;
  for (; e + 12 < end; e += 16) {
    int s0 = meta[e], s1 = meta[e + 4], s2 = meta[e + 8], s3 = meta[e + 12];
    unsigned u0 = ((const unsigned*)(rel8 + (size_t)s0 * DD))[i];
    unsigned u1 = ((const unsigned*)(rel8 + (size_t)s1 * DD))[i];
    unsigned u2 = ((const unsigned*)(rel8 + (size_t)s2 * DD))[i];
    unsigned u3 = ((const unsigned*)(rel8 + (size_t)s3 * DD))[i];
    a0 += f8b(u0, 0) + f8b(u1, 0) + f8b(u2, 0) + f8b(u3, 0);
    a1 += f8b(u0, 1) + f8b(u1, 1) + f8b(u2, 1) + f8b(u3, 1);
    a2 += f8b(u0, 2) + f8b(u1, 2) + f8b(u2, 2) + f8b(u3, 2);
    a3 += f8b(u0, 3) + f8b(u1, 3) + f8b(u2, 3) + f8b(u3, 3);
  }
  for (; e < end; e += 4) {
    int s0 = meta[e];
    unsigned u = ((const unsigned*)(rel8 + (size_t)s0 * DD))[i];
    a0 += f8b(u, 0); a1 += f8b(u, 1);
    a2 += f8b(u, 2); a3 += f8b(u, 3);
  }
  if (g) {
    red[g - 1][i][0] = a0; red[g - 1][i][1] = a1;
    red[g - 1][i][2] = a2; red[g - 1][i][3] = a3;
  }
  __syncthreads();
  if (g == 0) {
#pragma unroll
    for (int k = 0; k < 3; ++k) {
      a0 += red[k][i][0]; a1 += red[k][i][1];
      a2 += red[k][i][2]; a3 += red[k][i][3];
    }
    float inv = (end > beg) ? 1.f / (float)(end - beg) : 0.f;
    uint2 o;
    o.x = pack_bf2(a0 * inv, a1 * inv);
    o.y = pack_bf2(a2 * inv, a3 * inv);
    ((uint2*)(B1 + (size_t)n * 768))[i] = o;
  }
}

// ---------------- bf16 MFMA NT GEMM, double-buffered, XCD-chunked grid -----------
// 64x64 tile, 4 waves (each 32x32), BK=64, global_load_lds w=16, XOR-swizzled LDS.
// 1-D grid 768: wg=(bid&7)*96+(bid>>3); bm=wg/6, bn=wg%6.
// NOTE: 128^2 tile measured WORSE here (r11: 56us, 7% occ) — skinny-N shape needs
// the 768-block 64^2 grid.
// MODE 0: C = relu(acc + sum_r SC[row][r]*b_rel[r][col]) -> bf16 B1[:,384:768] + fp8 rel8
// MODE 1: h = relu(acc + deg?b_msg + b_self) + h (fp32), also h_f8 = fp8(h)
template <int MODE>
__global__ __launch_bounds__(256) void k_gemm_mfma(
    const short* __restrict__ A, int K, const short* __restrict__ Bp,
    const float* __restrict__ SC, const float* __restrict__ brel_l,
    const float* __restrict__ bmsg_l, const float* __restrict__ bself_l,
    const int* __restrict__ rp2, float* __restrict__ h,
    unsigned char* __restrict__ f8out, short* __restrict__ Cout) {
  __shared__ short As[2][64 * 64];   // 8KB per buffer: 64 rows x 8 chunks(16B)
  __shared__ short Bs[2][64 * 64];   // chunk q' of row r holds global chunk q'^(r&7)
  int tid = threadIdx.x;
  int lane = tid & 63;
  int w = tid >> 6;              // 0..3
  int wr = w >> 1, wc = w & 1;   // wave tile origin (wr*32, wc*32)
  int bid = blockIdx.x;          // 768
  int wg = ((bid & 7) * 96) + (bid >> 3);
  int bm = wg / 6, bn = wg - bm * 6;

  int r0 = (w << 3) + (lane >> 3);        // rows 0..31 (set 0); set 1 adds 32
  int qg = (lane & 7) ^ (r0 & 7);         // (r0+32)&7 == r0&7
  const short* Ag0 = A + (size_t)(bm * 64 + r0) * K + qg * 8;
  const short* Ag1 = A + (size_t)(bm * 64 + r0 + 32) * K + qg * 8;
  const short* Bg0 = Bp + (size_t)(bn * 64 + r0) * K + qg * 8;
  const short* Bg1 = Bp + (size_t)(bn * 64 + r0 + 32) * K + qg * 8;

  auto stage = [&](int bi, int k0) {
    gl_lds16(Ag0 + k0, &As[bi][w * 512]);
    gl_lds16(Ag1 + k0, &As[bi][2048 + w * 512]);
    gl_lds16(Bg0 + k0, &Bs[bi][w * 512]);
    gl_lds16(Bg1 + k0, &Bs[bi][2048 + w * 512]);
  };

  f32x4 acc[2][2] = {};
  int fr = lane & 15, fq = lane >> 4;
  int nt = K >> 6;
  stage(0, 0);
  __syncthreads();
  for (int t = 0; t < nt; ++t) {
    if (t + 1 < nt) stage((t + 1) & 1, (t + 1) << 6);
    const short* Ab = As[t & 1];
    const short* Bb = Bs[t & 1];
#pragma unroll
    for (int kk = 0; kk < 2; ++kk) {
      bf16x8 a[2], b[2];
#pragma unroll
      for (int i = 0; i < 2; ++i) {
        int r = wr * 32 + i * 16 + fr;
        int qs = (kk * 4 + fq) ^ (r & 7);
        a[i] = *(const bf16x8*)&Ab[r * 64 + qs * 8];
      }
#pragma unroll
      for (int j = 0; j < 2; ++j) {
        int r = wc * 32 + j * 16 + fr;
        int qs = (kk * 4 + fq) ^ (r & 7);
        b[j] = *(const bf16x8*)&Bb[r * 64 + qs * 8];
      }
#pragma unroll
      for (int i = 0; i < 2; ++i)
#pragma unroll
        for (int j = 0; j < 2; ++j)
          acc[i][j] = __builtin_amdgcn_mfma_f32_16x16x32_bf16(a[i], b[j], acc[i][j], 0, 0, 0);
    }
    __syncthreads();
  }

  int cr = (lane >> 4) * 4;
  int cc = lane & 15;
#pragma unroll
  for (int i = 0; i < 2; ++i) {
#pragma unroll
    for (int jj = 0; jj < 4; ++jj) {
      int row = bm * 64 + wr * 32 + i * 16 + cr + jj;
      if (MODE == 0) {
        float4 sc = *(const float4*)&SC[row * 4];
#pragma unroll
        for (int j = 0; j < 2; ++j) {
          int col = bn * 64 + wc * 32 + j * 16 + cc;
          float v = acc[i][j][jj] + sc.x * brel_l[col] + sc.y * brel_l[384 + col] +
                    sc.z * brel_l[768 + col] + sc.w * brel_l[1152 + col];
          float rl = fmaxf(v, 0.f);
          Cout[(size_t)row * 768 + 384 + col] = (short)f2bf(rl);
          f8out[(size_t)row * DD + col] = f2f8(rl);
        }
      } else {
        float bmul = (rp2[(row + 1) * 4] > rp2[row * 4]) ? 1.f : 0.f;
#pragma unroll
        for (int j = 0; j < 2; ++j) {
          int col = bn * 64 + wc * 32 + j * 16 + cc;
          float v = acc[i][j][jj] + bmul * bmsg_l[col] + bself_l[col];
          float o = fmaxf(v, 0.f) + h[(size_t)row * DD + col];
          h[(size_t)row * DD + col] = o;
          f8out[(size_t)row * DD + col] = f2f8(o);
        }
      }
    }
  }
}

// ---------------- final per-batch mean ----------------
__global__ void k_out(const float* __restrict__ h, float* __restrict__ out) {
  int b = blockIdx.x;   // 64
  int c = threadIdx.x;  // 384
  float s = 0.f;
  for (int j = 0; j < 128; ++j) s += h[(size_t)(b * 128 + j) * DD + c];
  out[b * DD + c] = s * (1.f / 128.f);
}

extern "C" void kernel_launch(void* const* d_in, const int* in_sizes, int n_in,
                              void* d_out, int out_size, void* d_ws, size_t ws_size,
                              hipStream_t stream) {
  const float* x      = (const float*)d_in[0];
  const int*   ei     = (const int*)d_in[1];
  const int*   et     = (const int*)d_in[2];
  const float* gamma  = (const float*)d_in[3];
  const float* beta   = (const float*)d_in[4];
  const float* W_rel  = (const float*)d_in[5];
  const float* b_rel  = (const float*)d_in[6];
  const float* nc     = (const float*)d_in[7];
  const float* W_msg  = (const float*)d_in[8];
  const float* b_msg  = (const float*)d_in[9];
  const float* W_self = (const float*)d_in[10];
  const float* b_self = (const float*)d_in[11];
  float* out = (float*)d_out;

  char* ws = (char*)d_ws;
  size_t off = 0;
  auto alloc = [&](size_t bytes) -> void* {
    void* p = ws + off;
    off = (off + bytes + 255) & ~(size_t)255;
    return p;
  };
  float* h      = (float*)alloc((size_t)NN * DD * 4);
  short* h_bf   = (short*)alloc((size_t)NN * DD * 2);
  unsigned char* h_f8 = (unsigned char*)alloc((size_t)NN * DD);
  unsigned char* rel8 = (unsigned char*)alloc((size_t)NN * DD);
  short* Agg    = (short*)alloc((size_t)NN * 1536 * 2);
  short* B1     = (short*)alloc((size_t)NN * 768 * 2);
  short* Wcat   = (short*)alloc((size_t)NL * 384 * 1536 * 2);
  short* Wcat2  = (short*)alloc((size_t)NL * 384 * 768 * 2);
  float* SC     = (float*)alloc((size_t)NN * 4 * 4);
  int*   meta   = (int*)alloc((size_t)NE * 4);
  float* wsort  = (float*)alloc((size_t)NE * 4);
  int*   rp2    = (int*)alloc((size_t)(NN * 4 + 1) * 4);
  int*   cursor = (int*)alloc((size_t)NN * 4 * 4);
  float* ninv   = (float*)alloc((size_t)NN * 4);
  char*  zb     = (char*)alloc(134144);  // musum|msqsum|c_rel contiguous, zeroed
  float* musum  = (float*)(zb);
  float* msqsum = (float*)(zb + 1536);
  int*   c_rel  = (int*)(zb + 3072);

  k_zero<<<(134144 / 16 + 255) / 256, 256, 0, stream>>>((uint4*)zb, 134144 / 16);
  k_pre<<<5547, 384, 0, stream>>>(x, musum, msqsum, ei, et, c_rel,
                                  W_rel, W_msg, W_self, Wcat, Wcat2);
  k_bn<<<NN, 64, 0, stream>>>(x, gamma, beta, musum, msqsum, h, h_bf, h_f8, ninv);
  k_scan<<<1, 1024, 0, stream>>>(c_rel, rp2, cursor);
  k_fill<<<NE / 256, 256, 0, stream>>>(ei, et, cursor, meta);
  k_we2<<<NN, 256, 0, stream>>>(h_bf, h_f8, ninv, rp2, meta, wsort);

  for (int l = 0; l < NL; ++l) {
    k_aggrel<<<NN, 384, 0, stream>>>(h_f8, rp2, meta, wsort, nc, Agg, SC, l);
    k_gemm_mfma<0><<<768, 256, 0, stream>>>(
        Agg, 1536, Wcat + (size_t)l * 384 * 1536, SC, b_rel + l * NR * DD,
        nullptr, nullptr, nullptr, nullptr, rel8, B1);
    k_aggmp<<<NN, 384, 0, stream>>>(B1, rel8, rp2, meta);
    k_gemm_mfma<1><<<768, 256, 0, stream>>>(
        B1, 768, Wcat2 + (size_t)l * 384 * 768, nullptr, nullptr,
        b_msg + l * DD, b_self + l * DD, rp2, h, h_f8, nullptr);
  }
  k_out<<<64, 384, 0, stream>>>(h, out);
}